// Round 8
// baseline (192.783 us; speedup 1.0000x reference)
//
#include <hip/hip_runtime.h>

typedef unsigned short u16;

#define NGRAPH 16
#define SEQ    1024
#define DIM    128
#define NHEAD  2
#define HDIM   64
#define KPOS   20
#define NTOT   (NGRAPH*SEQ)     // 16384
#define QKVD   (3*DIM)          // 384

// ---------- bf16 helpers ----------------------------------------------------
__device__ __forceinline__ float bf2f(u16 u) {
    return __uint_as_float(((unsigned int)u) << 16);
}
__device__ __forceinline__ u16 f2bf(float f) {
    unsigned int u = __float_as_uint(f);
    u += 0x7fffu + ((u >> 16) & 1u);   // RNE
    return (u16)(u >> 16);
}

// ---------- DPP 16-lane reductions (VALU, keeps DS pipe free) --------------
template<int CTRL>
__device__ __forceinline__ float dpp_ror(float x) {
    return __int_as_float(__builtin_amdgcn_update_dpp(
        __float_as_int(x), __float_as_int(x), CTRL, 0xF, 0xF, true));
}
__device__ __forceinline__ float row16_max(float x) {
    x = fmaxf(x, dpp_ror<0x121>(x));
    x = fmaxf(x, dpp_ror<0x122>(x));
    x = fmaxf(x, dpp_ror<0x124>(x));
    x = fmaxf(x, dpp_ror<0x128>(x));
    return x;
}
__device__ __forceinline__ float row16_sum(float x) {
    x += dpp_ror<0x121>(x);
    x += dpp_ror<0x122>(x);
    x += dpp_ror<0x124>(x);
    x += dpp_ror<0x128>(x);
    return x;
}

// ---------- dtype-adaptive input loads (fbf=1: bf16, fbf=0: f32) -----------
__device__ __forceinline__ float ld1(const void* p, int fbf, size_t i) {
    return fbf ? bf2f(((const u16*)p)[i]) : ((const float*)p)[i];
}
__device__ __forceinline__ float4 ldw8(const void* W, int fbf, size_t i) {
    if (fbf) return *(const float4*)((const u16*)W + i);
    const float* q = (const float*)W + i;
    float4 a = *(const float4*)q, b = *(const float4*)(q + 4);
    float4 r;
    u16* d = (u16*)&r;
    d[0]=f2bf(a.x); d[1]=f2bf(a.y); d[2]=f2bf(a.z); d[3]=f2bf(a.w);
    d[4]=f2bf(b.x); d[5]=f2bf(b.y); d[6]=f2bf(b.z); d[7]=f2bf(b.w);
    return r;
}

typedef __attribute__((ext_vector_type(8))) short bf16x8;
typedef __attribute__((ext_vector_type(4))) float f32x4;

// ---------- direct global->LDS (width 16), per-lane global addr ------------
__device__ __forceinline__ void gload16(const u16* g, u16* l) {
    __builtin_amdgcn_global_load_lds(
        (const __attribute__((address_space(1))) unsigned int*)(g),
        (__attribute__((address_space(3))) unsigned int*)(l), 16, 0, 0);
}
#define VMCNT0() asm volatile("s_waitcnt vmcnt(0)" ::: "memory")

// ---------- dtype detect ----------------------------------------------------
__device__ __forceinline__ int detect_bf16(const u16* x) {
    int ok = 1;
    for (int i = 0; i < 256; i += 2) {
        unsigned e = (x[i] >> 7) & 0xFF;
        if (e < 60u || e > 180u) ok = 0;
    }
    return ok;
}
__global__ void detect_kernel(const u16* __restrict__ x, int* __restrict__ flag) {
    if (threadIdx.x == 0 && blockIdx.x == 0) *flag = detect_bf16(x);
}

// ---------- K0: weight conversion to bf16 (+ self-detect, writes flag) -----
__global__ __launch_bounds__(256)
void wconv_kernel(const void* __restrict__ in_w, const void* __restrict__ out_w,
                  const void* __restrict__ ff1_w, const void* __restrict__ ff2_w,
                  const u16* __restrict__ x,
                  u16* __restrict__ wbf, int* __restrict__ flag) {
    __shared__ int fsh;
    if (threadIdx.x == 0) {
        int ok = detect_bf16(x);
        fsh = ok;
        if (blockIdx.x == 0) *flag = ok;
    }
    __syncthreads();
    int fbf = fsh;
    int i8 = (blockIdx.x * 256 + threadIdx.x) * 8;
    const void* src; int off;
    if      (i8 <  49152) { src = in_w;  off = i8; }
    else if (i8 <  65536) { src = out_w; off = i8 - 49152; }
    else if (i8 < 131072) { src = ff1_w; off = i8 - 65536; }
    else                  { src = ff2_w; off = i8 - 131072; }
    *(float4*)&wbf[i8] = ldw8(src, fbf, off);
}

// ---------- K1 (fallback only): pe ------------------------------------------
__global__ __launch_bounds__(256)
void pe_kernel(const void* __restrict__ x, const void* __restrict__ pos,
               const void* __restrict__ pe_w, const void* __restrict__ pe_b,
               u16* __restrict__ h0, const int* __restrict__ flag) {
    int fbf = *flag;
    __shared__ float wsh[DIM][KPOS + 1];
    int t = threadIdx.x;
    for (int i = t; i < DIM * KPOS; i += 256)
        wsh[i / KPOS][i % KPOS] = ld1(pe_w, fbf, i);
    __syncthreads();
    int row = blockIdx.x * 2 + (t >> 7), d = t & 127;
    float acc = 0.f;
#pragma unroll
    for (int k = 0; k < KPOS; ++k)
        acc += ld1(pos, fbf, (size_t)row * KPOS + k) * wsh[d][k];
    int rs = fbf ? 128 : 256;
    h0[(size_t)row * rs + d] =
        f2bf(ld1(x, fbf, (size_t)row * DIM + d) + acc + ld1(pe_b, fbf, d));
}

// ===========================================================================
// K2q (batched): FUSED pe + QKV GEMM (unchanged from R7).
// ===========================================================================
__global__ __launch_bounds__(256)
void qkvpe_kernel(const void* __restrict__ x, const void* __restrict__ pos,
                  const void* __restrict__ pe_w, const void* __restrict__ pe_b,
                  const u16* __restrict__ W, const void* __restrict__ bias,
                  u16* __restrict__ h0, u16* __restrict__ qkv,
                  u16* __restrict__ vt, const int* __restrict__ flag) {
    int fbf = *flag;
    int rs  = fbf ? 128 : 256;
    __shared__ __align__(16) u16 Ash[64][128];
    __shared__ __align__(16) u16 Wsh[2][128][128];
    __shared__ float wsh[DIM][KPOS + 1];
    __shared__ float possh[64][KPOS + 1];
    int t = threadIdx.x;
    int w = t >> 6, lane = t & 63, l16 = lane & 15, quad = lane >> 4;
    int n0 = blockIdx.x * 64;
    int xr = (l16 & 7) << 3;

    // issue W tile 0 early (flies under pe)
#pragma unroll
    for (int i = 0; i < 8; ++i) {
        int r = w * 4 + i * 16 + (lane >> 4);
        int s = (lane & 15) ^ (r & 7);
        gload16(&W[(size_t)r * 128 + s * 8], &Wsh[0][w * 4 + i * 16][0]);
    }
    for (int i = t; i < DIM * KPOS; i += 256)
        wsh[i / KPOS][i % KPOS] = ld1(pe_w, fbf, i);
    for (int i = t; i < 64 * KPOS; i += 256)
        possh[i / KPOS][i % KPOS] =
            ld1(pos, fbf, (size_t)(n0 + i / KPOS) * KPOS + i % KPOS);
    asm volatile("s_waitcnt lgkmcnt(0)" ::: "memory");
    __builtin_amdgcn_s_barrier();

    // pe: h0 tile -> Ash (XOR layout) + global (slot layout)
#pragma unroll
    for (int u = 0; u < 4; ++u) {
        int gu = t + u * 256;
        int r = gu >> 4, g = gu & 15;
        float4 hv;
        u16* hp = (u16*)&hv;
#pragma unroll
        for (int j = 0; j < 8; ++j) {
            int d = g * 8 + j;
            float a = ld1(x, fbf, (size_t)(n0 + r) * DIM + d) + ld1(pe_b, fbf, d);
#pragma unroll
            for (int k = 0; k < KPOS; ++k) a += possh[r][k] * wsh[d][k];
            hp[j] = f2bf(a);
        }
        *(float4*)&Ash[r][(g ^ (r & 7)) * 8] = hv;
        *(float4*)&h0[(size_t)(n0 + r) * rs + g * 8] = hv;
    }
    asm volatile("s_waitcnt lgkmcnt(0)" ::: "memory");
    __builtin_amdgcn_s_barrier();

#pragma unroll
    for (int m = 0; m < 3; ++m) {
        int m0 = m * 128;
        if (m < 2) {       // prefetch next W tile into other buffer
#pragma unroll
            for (int i = 0; i < 8; ++i) {
                int r = w * 4 + i * 16 + (lane >> 4);
                int s = (lane & 15) ^ (r & 7);
                gload16(&W[(size_t)(m0 + 128 + r) * 128 + s * 8],
                        &Wsh[(m + 1) & 1][w * 4 + i * 16][0]);
            }
            asm volatile("s_waitcnt vmcnt(8)" ::: "memory");
        } else {
            asm volatile("s_waitcnt vmcnt(0)" ::: "memory");
        }
        __builtin_amdgcn_s_barrier();
        f32x4 acc[8] = {};
        __builtin_amdgcn_s_setprio(1);
#pragma unroll
        for (int kk = 0; kk < 4; ++kk) {
            bf16x8 af = *(const bf16x8*)&Ash[w * 16 + l16][(kk * 32 + quad * 8) ^ xr];
#pragma unroll
            for (int s = 0; s < 8; ++s) {
                bf16x8 bf = *(const bf16x8*)&Wsh[m & 1][s * 16 + l16][(kk * 32 + quad * 8) ^ xr];
                acc[s] = __builtin_amdgcn_mfma_f32_16x16x32_bf16(af, bf, acc[s], 0, 0, 0);
            }
        }
        __builtin_amdgcn_s_setprio(0);
        float bb[8];
#pragma unroll
        for (int s = 0; s < 8; ++s) bb[s] = ld1(bias, fbf, m0 + s * 16 + l16);
#pragma unroll
        for (int r = 0; r < 4; ++r) {
            int lr = w * 16 + quad * 4 + r;
            if (m == 2) {          // V: store transposed vt[(b*128+d)*SEQ + n]
                int n = n0 + lr;
                int bg = n >> 10, nl = n & 1023;
#pragma unroll
                for (int s = 0; s < 8; ++s)
                    vt[((size_t)(bg * 128) + s * 16 + l16) * SEQ + nl] =
                        f2bf(acc[s][r] + bb[s]);
            } else {
#pragma unroll
                for (int s = 0; s < 8; ++s)
                    qkv[(size_t)(n0 + lr) * QKVD + m0 + s * 16 + l16] =
                        f2bf(acc[s][r] + bb[s]);
            }
        }
        if (m < 2) __builtin_amdgcn_s_barrier();   // Wsh reuse guard
    }
}

// ===========================================================================
// K3 (batched): FUSED attention (both heads) + out-proj + LN1.
// One block per (graph, q-tile): grid 256 x 256thr. Heads processed
// sequentially with the R5 attention structure (gload_lds K/V dbuf, XOR
// swizzle, DPP softmax); per-head ctx written to CtxSh in gload-XOR layout
// (same write/read pair as R7's F1sh). out_w staged into its own Wsh at
// kernel START so its HBM latency hides under all of attention. Then
// GEMM K=128 + bias + h0-resid + LN1 -> h01, math identical to old
// mgemm2<2,1>. Deletes one dispatch + the 16MB ctx HBM round-trip.
// LDS 100352 B -> 1 blk/CU (R7 ffn proved 147KB static works).
// ===========================================================================
__global__ __launch_bounds__(256)
void attnout_kernel(const u16* __restrict__ qkv, const u16* __restrict__ vtp,
                    const u16* __restrict__ Wout, const void* __restrict__ out_b,
                    const void* __restrict__ lng, const void* __restrict__ lnb,
                    u16* __restrict__ h01, const int* __restrict__ flag) {
    int fbf = *flag;
    int rs  = fbf ? 128 : 256;
    __shared__ __align__(16) u16 Qsh[64][72];
    __shared__ __align__(16) u16 Ksh[2][64][64];
    __shared__ __align__(16) u16 Vsh[2][64][64];
    __shared__ u16 Psh[64][72];
    __shared__ __align__(16) u16 CtxSh[64][128];
    __shared__ __align__(16) u16 Wsh[128][128];
    int t    = threadIdx.x;
    int w    = t >> 6;
    int lane = t & 63;
    int l16  = lane & 15;
    int quad = lane >> 4;
    int xr   = (l16 & 7) << 3;
    int L = blockIdx.x;
    // XCD swizzle over 256 blocks: L%8 -> graph%8
    int g8 = L & 7; int rest = L >> 3;
    int qt = rest & 15; int b = (rest >> 4) * 8 + g8;
    int n0 = b * SEQ + qt * 64;   // global row of this q-tile

    // stage out_w NOW -- completes long before the GEMM needs it
#pragma unroll
    for (int i = 0; i < 8; ++i) {
        int r = w * 4 + i * 16 + (lane >> 4);
        int s = (lane & 15) ^ (r & 7);
        gload16(&Wout[(size_t)r * 128 + s * 8], &Wsh[w * 4 + i * 16][0]);
    }

#pragma unroll 1
    for (int h = 0; h < NHEAD; ++h) {
        // ---- stage Q (pre-scaled by 0.125, exact exponent shift) ----
#pragma unroll
        for (int i = 0; i < 2; ++i) {
            int idx = t + i * 256;
            int r = idx >> 3, d8 = (idx & 7) * 8;
            float4 qv = *(const float4*)&qkv[(size_t)(n0 + r) * QKVD + h * HDIM + d8];
            u16* qp = (u16*)&qv;
#pragma unroll
            for (int j = 0; j < 8; ++j) qp[j] = f2bf(bf2f(qp[j]) * 0.125f);
            *(float4*)&Qsh[r][d8] = qv;
        }
        const u16* kbase = qkv + (size_t)b * SEQ * QKVD + DIM + h * HDIM;
        const u16* vbase = vtp + (size_t)((b * 2 + h) * 64) * SEQ;

        auto stageKV = [&](int kt, int bf2) {
#pragma unroll
            for (int i = 0; i < 2; ++i) {
                int r = w * 8 + i * 32 + (lane >> 3);
                int s = (lane & 7) ^ (r & 7);
                gload16(&kbase[(size_t)(kt * 64 + r) * QKVD + s * 8],
                        &Ksh[bf2][w * 8 + i * 32][0]);
            }
#pragma unroll
            for (int i = 0; i < 2; ++i) {
                int r = w * 8 + i * 32 + (lane >> 3);
                int s = (lane & 7) ^ (r & 7);
                gload16(&vbase[(size_t)r * SEQ + kt * 64 + s * 8],
                        &Vsh[bf2][w * 8 + i * 32][0]);
            }
        };

        stageKV(0, 0);
        VMCNT0();
        __syncthreads();
        bf16x8 qa0 = *(const bf16x8*)&Qsh[w * 16 + l16][quad * 8];
        bf16x8 qa1 = *(const bf16x8*)&Qsh[w * 16 + l16][32 + quad * 8];

        f32x4 o[4] = {};
        float mrow[4] = {-1e30f, -1e30f, -1e30f, -1e30f};
        float lrow[4] = {};

#pragma unroll 1
        for (int kt = 0; kt < SEQ / 64; ++kt) {
            int cur = kt & 1;
            if (kt + 1 < SEQ / 64) stageKV(kt + 1, cur ^ 1);

            float sc[4][4];
            __builtin_amdgcn_s_setprio(1);
#pragma unroll
            for (int c = 0; c < 4; ++c) {
                bf16x8 kb0 = *(const bf16x8*)&Ksh[cur][c * 16 + l16][(quad * 8) ^ xr];
                bf16x8 kb1 = *(const bf16x8*)&Ksh[cur][c * 16 + l16][(32 + quad * 8) ^ xr];
                f32x4 s = {};
                s = __builtin_amdgcn_mfma_f32_16x16x32_bf16(qa0, kb0, s, 0, 0, 0);
                s = __builtin_amdgcn_mfma_f32_16x16x32_bf16(qa1, kb1, s, 0, 0, 0);
#pragma unroll
                for (int r = 0; r < 4; ++r) sc[c][r] = s[r];
            }
            __builtin_amdgcn_s_setprio(0);
            float alpha[4];
#pragma unroll
            for (int r = 0; r < 4; ++r) {
                float mx = fmaxf(fmaxf(sc[0][r], sc[1][r]), fmaxf(sc[2][r], sc[3][r]));
                mx = row16_max(mx);
                float mnew = fmaxf(mrow[r], mx);
                alpha[r] = __expf(mrow[r] - mnew);
                mrow[r] = mnew;
                float sum = 0.f;
#pragma unroll
                for (int c = 0; c < 4; ++c) {
                    float p = __expf(sc[c][r] - mnew);
                    sc[c][r] = p;
                    sum += p;
                }
                sum = row16_sum(sum);
                lrow[r] = lrow[r] * alpha[r] + sum;
            }
#pragma unroll
            for (int c = 0; c < 4; ++c)
#pragma unroll
                for (int r = 0; r < 4; ++r)
                    Psh[w * 16 + quad * 4 + r][c * 16 + l16] = f2bf(sc[c][r]);
#pragma unroll
            for (int dt = 0; dt < 4; ++dt)
#pragma unroll
                for (int r = 0; r < 4; ++r) o[dt][r] *= alpha[r];
            bf16x8 pa0 = *(const bf16x8*)&Psh[w * 16 + l16][quad * 8];
            bf16x8 pa1 = *(const bf16x8*)&Psh[w * 16 + l16][32 + quad * 8];
            __builtin_amdgcn_s_setprio(1);
#pragma unroll
            for (int dt = 0; dt < 4; ++dt) {
                bf16x8 vb0 = *(const bf16x8*)&Vsh[cur][dt * 16 + l16][(quad * 8) ^ xr];
                bf16x8 vb1 = *(const bf16x8*)&Vsh[cur][dt * 16 + l16][(32 + quad * 8) ^ xr];
                o[dt] = __builtin_amdgcn_mfma_f32_16x16x32_bf16(pa0, vb0, o[dt], 0, 0, 0);
                o[dt] = __builtin_amdgcn_mfma_f32_16x16x32_bf16(pa1, vb1, o[dt], 0, 0, 0);
            }
            __builtin_amdgcn_s_setprio(0);
            if (kt + 1 < SEQ / 64) {
                VMCNT0();
                __syncthreads();
            }
        }
        // ---- normalize, write ctx tile into CtxSh (gload-XOR layout) ----
#pragma unroll
        for (int r = 0; r < 4; ++r) {
            float inv = 1.f / lrow[r];
            int lr = w * 16 + quad * 4 + r;
#pragma unroll
            for (int dt = 0; dt < 4; ++dt) {
                int e = h * HDIM + dt * 16 + l16;       // column 0..127
                int g = e >> 3;
                CtxSh[lr][((g ^ (lr & 7)) << 3) + (e & 7)] =
                    f2bf(o[dt][r] * inv);
            }
        }
        __syncthreads();   // Qsh/Ksh/Vsh reuse by next head; CtxSh complete
    }

    // ---- out-proj GEMM (K=128) + bias + resid(h0) + LN1 -> h01 ----
    VMCNT0();              // Wsh staged at kernel start (long since landed)
    f32x4 acc[8] = {};
    __builtin_amdgcn_s_setprio(1);
#pragma unroll
    for (int kk = 0; kk < 4; ++kk) {
        bf16x8 af = *(const bf16x8*)&CtxSh[w * 16 + l16][(kk * 32 + quad * 8) ^ xr];
#pragma unroll
        for (int s = 0; s < 8; ++s) {
            bf16x8 bf = *(const bf16x8*)&Wsh[s * 16 + l16][(kk * 32 + quad * 8) ^ xr];
            acc[s] = __builtin_amdgcn_mfma_f32_16x16x32_bf16(af, bf, acc[s], 0, 0, 0);
        }
    }
    __builtin_amdgcn_s_setprio(0);
    float bb[8], gg[8], be[8];
#pragma unroll
    for (int s = 0; s < 8; ++s) {
        bb[s] = ld1(out_b, fbf, s * 16 + l16);
        gg[s] = ld1(lng, fbf, s * 16 + l16);
        be[s] = ld1(lnb, fbf, s * 16 + l16);
    }
#pragma unroll
    for (int r = 0; r < 4; ++r) {
        int lr = w * 16 + quad * 4 + r;
        size_t rg = (size_t)(n0 + lr);
        float v[8];
#pragma unroll
        for (int s = 0; s < 8; ++s)
            v[s] = acc[s][r] + bb[s] + bf2f(h01[rg * rs + s * 16 + l16]);
        float sm = 0.f, sq = 0.f;
#pragma unroll
        for (int s = 0; s < 8; ++s) { sm += v[s]; sq += v[s] * v[s]; }
        sm = row16_sum(sm);
        sq = row16_sum(sq);
        float mu  = sm * (1.f / DIM);
        float var = fmaxf(sq * (1.f / DIM) - mu * mu, 0.f);
        float rsq = rsqrtf(var + 1e-5f);
#pragma unroll
        for (int s = 0; s < 8; ++s)
            h01[rg * rs + s * 16 + l16] =
                f2bf((v[s] - mu) * rsq * gg[s] + be[s]);
    }
}

// ===========================================================================
// K5 (batched): FUSED FFN (unchanged from R7).
// ===========================================================================
__global__ __launch_bounds__(256)
void ffn_kernel(const u16* __restrict__ h1, const u16* __restrict__ W1,
                const u16* __restrict__ W2, const void* __restrict__ b1,
                const void* __restrict__ b2,
                const void* __restrict__ lng, const void* __restrict__ lnb,
                void* __restrict__ outp, const int* __restrict__ flag) {
    int fbf = *flag;
    int rs  = fbf ? 128 : 256;
    __shared__ __align__(16) u16 Ash[64][128];
    __shared__ __align__(16) u16 Wsh[2][128][128];
    __shared__ __align__(16) u16 F1sh[4][64][128];
    int t = threadIdx.x;
    int w = t >> 6, lane = t & 63, l16 = lane & 15, quad = lane >> 4;
    int n0 = blockIdx.x * 64;
    int xr = (l16 & 7) << 3;

    // stage A (h1 tile) + W1 chunk 0
#pragma unroll
    for (int i = 0; i < 4; ++i) {
        int r = w * 4 + i * 16 + (lane >> 4);
        int s = (lane & 15) ^ (r & 7);
        gload16(&h1[(size_t)(n0 + r) * rs + s * 8], &Ash[w * 4 + i * 16][0]);
    }
#pragma unroll
    for (int i = 0; i < 8; ++i) {
        int r = w * 4 + i * 16 + (lane >> 4);
        int s = (lane & 15) ^ (r & 7);
        gload16(&W1[(size_t)r * 128 + s * 8], &Wsh[0][w * 4 + i * 16][0]);
    }

    // ---- GEMM1: 4 column tiles of ff1 -> F1sh (relu+bias, XOR layout) ----
#pragma unroll
    for (int m = 0; m < 4; ++m) {
#pragma unroll
        for (int i = 0; i < 8; ++i) {
            int r = w * 4 + i * 16 + (lane >> 4);
            int s = (lane & 15) ^ (r & 7);
            if (m < 3)
                gload16(&W1[(size_t)((m + 1) * 128 + r) * 128 + s * 8],
                        &Wsh[(m + 1) & 1][w * 4 + i * 16][0]);
            else
                gload16(&W2[(size_t)r * 512 + s * 8],
                        &Wsh[0][w * 4 + i * 16][0]);
        }
        asm volatile("s_waitcnt vmcnt(8)" ::: "memory");
        __builtin_amdgcn_s_barrier();
        f32x4 acc[8] = {};
        __builtin_amdgcn_s_setprio(1);
#pragma unroll
        for (int kk = 0; kk < 4; ++kk) {
            bf16x8 af = *(const bf16x8*)&Ash[w * 16 + l16][(kk * 32 + quad * 8) ^ xr];
#pragma unroll
            for (int s = 0; s < 8; ++s) {
                bf16x8 bf = *(const bf16x8*)&Wsh[m & 1][s * 16 + l16][(kk * 32 + quad * 8) ^ xr];
                acc[s] = __builtin_amdgcn_mfma_f32_16x16x32_bf16(af, bf, acc[s], 0, 0, 0);
            }
        }
        __builtin_amdgcn_s_setprio(0);
        float bb[8];
#pragma unroll
        for (int s = 0; s < 8; ++s) bb[s] = ld1(b1, fbf, m * 128 + s * 16 + l16);
#pragma unroll
        for (int r = 0; r < 4; ++r) {
            int lr = w * 16 + quad * 4 + r;
#pragma unroll
            for (int s = 0; s < 8; ++s) {
                int g = s * 2 + (l16 >> 3);
                F1sh[m][lr][((g ^ (lr & 7)) << 3) + (l16 & 7)] =
                    f2bf(fmaxf(acc[s][r] + bb[s], 0.f));
            }
        }
        asm volatile("s_waitcnt lgkmcnt(0)" ::: "memory");
        __builtin_amdgcn_s_barrier();
    }

    // ---- GEMM2: out = f1 @ ff2^T, K=512 in 4 LDS chunks ----
    f32x4 acc2[8] = {};
#pragma unroll
    for (int c = 0; c < 4; ++c) {
        if (c < 3) {
#pragma unroll
            for (int i = 0; i < 8; ++i) {
                int r = w * 4 + i * 16 + (lane >> 4);
                int s = (lane & 15) ^ (r & 7);
                gload16(&W2[(size_t)r * 512 + (c + 1) * 128 + s * 8],
                        &Wsh[(c + 1) & 1][w * 4 + i * 16][0]);
            }
            asm volatile("s_waitcnt vmcnt(8)" ::: "memory");
        } else {
            asm volatile("s_waitcnt vmcnt(0)" ::: "memory");
        }
        __builtin_amdgcn_s_barrier();
        __builtin_amdgcn_s_setprio(1);
#pragma unroll
        for (int kk = 0; kk < 4; ++kk) {
            bf16x8 af = *(const bf16x8*)&F1sh[c][w * 16 + l16][(kk * 32 + quad * 8) ^ xr];
#pragma unroll
            for (int s = 0; s < 8; ++s) {
                bf16x8 bf = *(const bf16x8*)&Wsh[c & 1][s * 16 + l16][(kk * 32 + quad * 8) ^ xr];
                acc2[s] = __builtin_amdgcn_mfma_f32_16x16x32_bf16(af, bf, acc2[s], 0, 0, 0);
            }
        }
        __builtin_amdgcn_s_setprio(0);
        if (c < 3) __builtin_amdgcn_s_barrier();
    }

    // ---- LN2 epilogue: +b2 +resid(h1 from Ash) -> final out ----
    float bb[8], gg[8], be[8];
#pragma unroll
    for (int s = 0; s < 8; ++s) {
        bb[s] = ld1(b2, fbf, s * 16 + l16);
        gg[s] = ld1(lng, fbf, s * 16 + l16);
        be[s] = ld1(lnb, fbf, s * 16 + l16);
    }
#pragma unroll
    for (int r = 0; r < 4; ++r) {
        int lr = w * 16 + quad * 4 + r;
        size_t rg = (size_t)(n0 + lr);
        float v[8];
#pragma unroll
        for (int s = 0; s < 8; ++s) {
            int g = s * 2 + (l16 >> 3);
            float resid = bf2f(Ash[lr][((g ^ (lr & 7)) << 3) + (l16 & 7)]);
            v[s] = acc2[s][r] + bb[s] + resid;
        }
        float sm = 0.f, sq = 0.f;
#pragma unroll
        for (int s = 0; s < 8; ++s) { sm += v[s]; sq += v[s] * v[s]; }
        sm = row16_sum(sm);
        sq = row16_sum(sq);
        float mu  = sm * (1.f / DIM);
        float var = fmaxf(sq * (1.f / DIM) - mu * mu, 0.f);
        float rsq = rsqrtf(var + 1e-5f);
        if (fbf) {
            u16* o = (u16*)outp;
#pragma unroll
            for (int s = 0; s < 8; ++s)
                o[rg * 128 + s * 16 + l16] =
                    f2bf((v[s] - mu) * rsq * gg[s] + be[s]);
        } else {
            float* o = (float*)outp;
#pragma unroll
            for (int s = 0; s < 8; ++s)
                o[rg * 128 + s * 16 + l16] =
                    (v[s] - mu) * rsq * gg[s] + be[s];
        }
    }
}

// ============================================================================
//                 LEGACY KERNELS (per-graph fallback path)
// ============================================================================
template<int EPI, int NK>
__global__ __launch_bounds__(256)
void mgemm_kernel(const u16* __restrict__ A, const void* __restrict__ W,
                  int wbf16, const void* __restrict__ bias,
                  const u16* __restrict__ resid,
                  const void* __restrict__ lng, const void* __restrict__ lnb,
                  void* __restrict__ outp, u16* __restrict__ vt,
                  int Mtot, int AstrIn,
                  int arow0, int orow0, const int* __restrict__ flag) {
    const int K = NK * 128;
    int fbf  = *flag;
    int wfmt = wbf16 ? 1 : fbf;
    int rs   = fbf ? 128 : 256;
    int Astr = (AstrIn < 0) ? rs : AstrIn;
    __shared__ u16 Ash[64][136];
    __shared__ u16 Wsh[128][136];
    int t = threadIdx.x;
    int w = t >> 6, lane = t & 63, l16 = lane & 15, quad = lane >> 4;
    int n0 = blockIdx.x * 64;
    int m0 = blockIdx.y * 128;
    f32x4 acc[8] = {};
    float4 aR[4], wR[8];
#pragma unroll
    for (int i = 0; i < 4; ++i) {
        int idx = t + i * 256;
        int row = idx >> 4, k8 = (idx & 15) * 8;
        aR[i] = *(const float4*)&A[(size_t)(arow0 + n0 + row) * Astr + k8];
    }
#pragma unroll
    for (int i = 0; i < 8; ++i) {
        int idx = t + i * 256;
        int row = idx >> 4, k8 = (idx & 15) * 8;
        wR[i] = ldw8(W, wfmt, (size_t)(m0 + row) * K + k8);
    }
#pragma unroll 1
    for (int c = 0; c < NK; ++c) {
#pragma unroll
        for (int i = 0; i < 4; ++i) {
            int idx = t + i * 256;
            *(float4*)&Ash[idx >> 4][(idx & 15) * 8] = aR[i];
        }
#pragma unroll
        for (int i = 0; i < 8; ++i) {
            int idx = t + i * 256;
            *(float4*)&Wsh[idx >> 4][(idx & 15) * 8] = wR[i];
        }
        __syncthreads();
        if (c + 1 < NK) {
            int kc = (c + 1) * 128;
#pragma unroll
            for (int i = 0; i < 4; ++i) {
                int idx = t + i * 256;
                int row = idx >> 4, k8 = (idx & 15) * 8;
                aR[i] = *(const float4*)&A[(size_t)(arow0 + n0 + row) * Astr + kc + k8];
            }
#pragma unroll
            for (int i = 0; i < 8; ++i) {
                int idx = t + i * 256;
                int row = idx >> 4, k8 = (idx & 15) * 8;
                wR[i] = ldw8(W, wfmt, (size_t)(m0 + row) * K + kc + k8);
            }
        }
        __builtin_amdgcn_s_setprio(1);
#pragma unroll
        for (int kk = 0; kk < 4; ++kk) {
            bf16x8 af = *(const bf16x8*)&Ash[w * 16 + l16][kk * 32 + quad * 8];
#pragma unroll
            for (int s = 0; s < 8; ++s) {
                bf16x8 bf = *(const bf16x8*)&Wsh[s * 16 + l16][kk * 32 + quad * 8];
                acc[s] = __builtin_amdgcn_mfma_f32_16x16x32_bf16(af, bf, acc[s], 0, 0, 0);
            }
        }
        __builtin_amdgcn_s_setprio(0);
        if (c + 1 < NK) __syncthreads();
    }
    float bb[8];
#pragma unroll
    for (int s = 0; s < 8; ++s) bb[s] = ld1(bias, fbf, m0 + s * 16 + l16);
    float gg[8], be[8];
    if (EPI >= 2) {
#pragma unroll
        for (int s = 0; s < 8; ++s) {
            gg[s] = ld1(lng, fbf, s * 16 + l16);
            be[s] = ld1(lnb, fbf, s * 16 + l16);
        }
    }
#pragma unroll
    for (int r = 0; r < 4; ++r) {
        int lr = w * 16 + quad * 4 + r;
        float v[8];
#pragma unroll
        for (int s = 0; s < 8; ++s) {
            v[s] = acc[s][r] + bb[s];
            if (EPI == 1) v[s] = fmaxf(v[s], 0.f);
        }
        if (EPI <= 1) {
            u16* o = (u16*)outp;
#pragma unroll
            for (int s = 0; s < 8; ++s)
                o[(size_t)(n0 + lr) * Mtot + m0 + s * 16 + l16] = f2bf(v[s]);
        } else {
            size_t rg = (size_t)(orow0 + n0 + lr);
#pragma unroll
            for (int s = 0; s < 8; ++s)
                v[s] += bf2f(resid[rg * rs + s * 16 + l16]);
            float sm = 0.f, sq = 0.f;
#pragma unroll
            for (int s = 0; s < 8; ++s) { sm += v[s]; sq += v[s] * v[s]; }
            sm = row16_sum(sm);
            sq = row16_sum(sq);
            float mu  = sm * (1.f / DIM);
            float var = fmaxf(sq * (1.f / DIM) - mu * mu, 0.f);
            float rsq = rsqrtf(var + 1e-5f);
            if (EPI == 2) {
                u16* o = (u16*)outp;
#pragma unroll
                for (int s = 0; s < 8; ++s)
                    o[rg * rs + s * 16 + l16] =
                        f2bf((v[s] - mu) * rsq * gg[s] + be[s]);
            } else {
                if (fbf) {
                    u16* o = (u16*)outp;
#pragma unroll
                    for (int s = 0; s < 8; ++s)
                        o[rg * 128 + s * 16 + l16] =
                            f2bf((v[s] - mu) * rsq * gg[s] + be[s]);
                } else {
                    float* o = (float*)outp;
#pragma unroll
                    for (int s = 0; s < 8; ++s)
                        o[rg * 128 + s * 16 + l16] =
                            (v[s] - mu) * rsq * gg[s] + be[s];
                }
            }
        }
    }
}

__global__ __launch_bounds__(256)
void attn_lds_kernel(const u16* __restrict__ qkv, u16* __restrict__ ctx) {
    __shared__ u16 Qsh[64][72];
    __shared__ u16 Ksh[64][72];
    __shared__ u16 VshT[64][72];
    __shared__ u16 Psh[64][72];
    int t    = threadIdx.x;
    int w    = t >> 6;
    int lane = t & 63;
    int l16  = lane & 15;
    int quad = lane >> 4;
    int L = blockIdx.x;
    int qt = L & 15, gh = L >> 4;
    int b = gh >> 1, h = gh & 1;

#pragma unroll
    for (int i = 0; i < 2; ++i) {
        int idx = t + i * 256;
        int r = idx >> 3, d8 = (idx & 7) * 8;
        size_t n = (size_t)b * SEQ + qt * 64 + r;
        float4 qv = *(const float4*)&qkv[n * QKVD + h * HDIM + d8];
        u16* qp = (u16*)&qv;
#pragma unroll
        for (int j = 0; j < 8; ++j) qp[j] = f2bf(bf2f(qp[j]) * 0.125f);
        *(float4*)&Qsh[r][d8] = qv;
    }
    int kr = t >> 3, kd8 = (t & 7) * 8;
    int vr = t & 63, vdb = (t >> 6) * 16;
    float4 kR[2], vR[2];
    {
        size_t nk0 = (size_t)b * SEQ + kr;
        kR[0] = *(const float4*)&qkv[nk0 * QKVD + DIM + h * HDIM + kd8];
        kR[1] = *(const float4*)&qkv[(nk0 + 32) * QKVD + DIM + h * HDIM + kd8];
        size_t nv0 = (size_t)b * SEQ + vr;
        vR[0] = *(const float4*)&qkv[nv0 * QKVD + 2 * DIM + h * HDIM + vdb];
        vR[1] = *(const float4*)&qkv[nv0 * QKVD + 2 * DIM + h * HDIM + vdb + 8];
    }
    __syncthreads();
    bf16x8 qa0 = *(const bf16x8*)&Qsh[w * 16 + l16][quad * 8];
    bf16x8 qa1 = *(const bf16x8*)&Qsh[w * 16 + l16][32 + quad * 8];

    f32x4 o[4] = {};
    float mrow[4] = {-1e30f, -1e30f, -1e30f, -1e30f};
    float lrow[4] = {};

#pragma unroll 1
    for (int kt = 0; kt < SEQ / 64; ++kt) {
        *(float4*)&Ksh[kr][kd8]      = kR[0];
        *(float4*)&Ksh[kr + 32][kd8] = kR[1];
        {
            const u16* pa = (const u16*)&vR[0];
            const u16* pb = (const u16*)&vR[1];
#pragma unroll
            for (int j = 0; j < 8; ++j) VshT[vdb + j][vr] = pa[j];
#pragma unroll
            for (int j = 0; j < 8; ++j) VshT[vdb + 8 + j][vr] = pb[j];
        }
        __syncthreads();
        if (kt + 1 < SEQ / 64) {
            size_t nk0 = (size_t)b * SEQ + (kt + 1) * 64 + kr;
            kR[0] = *(const float4*)&qkv[nk0 * QKVD + DIM + h * HDIM + kd8];
            kR[1] = *(const float4*)&qkv[(nk0 + 32) * QKVD + DIM + h * HDIM + kd8];
            size_t nv0 = (size_t)b * SEQ + (kt + 1) * 64 + vr;
            vR[0] = *(const float4*)&qkv[nv0 * QKVD + 2 * DIM + h * HDIM + vdb];
            vR[1] = *(const float4*)&qkv[nv0 * QKVD + 2 * DIM + h * HDIM + vdb + 8];
        }
        float sc[4][4];
        __builtin_amdgcn_s_setprio(1);
#pragma unroll
        for (int c = 0; c < 4; ++c) {
            bf16x8 kb0 = *(const bf16x8*)&Ksh[c * 16 + l16][quad * 8];
            bf16x8 kb1 = *(const bf16x8*)&Ksh[c * 16 + l16][32 + quad * 8];
            f32x4 s = {};
            s = __builtin_amdgcn_mfma_f32_16x16x32_bf16(qa0, kb0, s, 0, 0, 0);
            s = __builtin_amdgcn_mfma_f32_16x16x32_bf16(qa1, kb1, s, 0, 0, 0);
#pragma unroll
            for (int r = 0; r < 4; ++r) sc[c][r] = s[r];
        }
        __builtin_amdgcn_s_setprio(0);
        float alpha[4];
#pragma unroll
        for (int r = 0; r < 4; ++r) {
            float mx = fmaxf(fmaxf(sc[0][r], sc[1][r]), fmaxf(sc[2][r], sc[3][r]));
            mx = row16_max(mx);
            float mnew = fmaxf(mrow[r], mx);
            alpha[r] = __expf(mrow[r] - mnew);
            mrow[r] = mnew;
            float sum = 0.f;
#pragma unroll
            for (int c = 0; c < 4; ++c) {
                float p = __expf(sc[c][r] - mnew);
                sc[c][r] = p;
                sum += p;
            }
            sum = row16_sum(sum);
            lrow[r] = lrow[r] * alpha[r] + sum;
        }
#pragma unroll
        for (int c = 0; c < 4; ++c)
#pragma unroll
            for (int r = 0; r < 4; ++r)
                Psh[w * 16 + quad * 4 + r][c * 16 + l16] = f2bf(sc[c][r]);
#pragma unroll
        for (int dt = 0; dt < 4; ++dt)
#pragma unroll
            for (int r = 0; r < 4; ++r) o[dt][r] *= alpha[r];
        bf16x8 pa0 = *(const bf16x8*)&Psh[w * 16 + l16][quad * 8];
        bf16x8 pa1 = *(const bf16x8*)&Psh[w * 16 + l16][32 + quad * 8];
        __builtin_amdgcn_s_setprio(1);
#pragma unroll
        for (int dt = 0; dt < 4; ++dt) {
            bf16x8 vb0 = *(const bf16x8*)&VshT[dt * 16 + l16][quad * 8];
            bf16x8 vb1 = *(const bf16x8*)&VshT[dt * 16 + l16][32 + quad * 8];
            o[dt] = __builtin_amdgcn_mfma_f32_16x16x32_bf16(pa0, vb0, o[dt], 0, 0, 0);
            o[dt] = __builtin_amdgcn_mfma_f32_16x16x32_bf16(pa1, vb1, o[dt], 0, 0, 0);
        }
        __builtin_amdgcn_s_setprio(0);
        __syncthreads();
    }
#pragma unroll
    for (int r = 0; r < 4; ++r) {
        float inv = 1.f / lrow[r];
        size_t n = (size_t)b * SEQ + qt * 64 + w * 16 + quad * 4 + r;
#pragma unroll
        for (int dt = 0; dt < 4; ++dt)
            ctx[n * DIM + h * HDIM + dt * 16 + l16] = f2bf(o[dt][r] * inv);
    }
}

// ---------------------------------------------------------------------------
extern "C" void kernel_launch(void* const* d_in, const int* in_sizes, int n_in,
                              void* d_out, int out_size, void* d_ws, size_t ws_size,
                              hipStream_t stream) {
    const void* x     = d_in[0];
    const void* pos   = d_in[1];
    const void* pe_w  = d_in[2];
    const void* pe_b  = d_in[3];
    const void* in_w  = d_in[4];
    const void* in_b  = d_in[5];
    const void* out_w = d_in[6];
    const void* out_b = d_in[7];
    const void* ln1_g = d_in[8];
    const void* ln1_b = d_in[9];
    const void* ln2_g = d_in[10];
    const void* ln2_b = d_in[11];
    const void* ff1_w = d_in[12];
    const void* ff1_b = d_in[13];
    const void* ff2_w = d_in[14];
    const void* ff2_b = d_in[15];

    char* wsb  = (char*)d_ws;
    int*  flag = (int*)(wsb + ((ws_size - 4) & ~(size_t)3));
    u16*  h01  = (u16*)d_out;   // h0 then h1, bf16 in dtype-dependent row slots
    const size_t MB = 1024 * 1024;

    if (ws_size >= 21 * MB) {
        // batched path: qkv[0,12M), vt[16,20M), wbf[20M,+384K)
        u16* qkv = (u16*)wsb;
        u16* vt  = (u16*)(wsb + 16 * MB);
        u16* wbf = (u16*)(wsb + 20 * MB);
        u16* wb_in  = wbf;
        u16* wb_out = wbf + 49152;
        u16* wb_ff1 = wbf + 65536;
        u16* wb_ff2 = wbf + 131072;

        wconv_kernel<<<96, 256, 0, stream>>>(in_w, out_w, ff1_w, ff2_w,
                                             (const u16*)x, wbf, flag);
        qkvpe_kernel<<<NTOT / 64, 256, 0, stream>>>(
            x, pos, pe_w, pe_b, wb_in, in_b, h01, qkv, vt, flag);
        attnout_kernel<<<NTOT / 64, 256, 0, stream>>>(
            qkv, vt, wb_out, out_b, ln1_g, ln1_b, h01, flag);
        ffn_kernel<<<NTOT / 64, 256, 0, stream>>>(
            h01, wb_ff1, wb_ff2, ff1_b, ff2_b, ln2_g, ln2_b, d_out, flag);
    } else {
        // per-graph path (legacy): qkv_g[0,768K), ctx_g[768K,1M); f1_g reuse
        u16* qkv_g = (u16*)wsb;
        u16* ctx_g = (u16*)(wsb + 768 * 1024);
        u16* f1_g  = (u16*)wsb;
        detect_kernel<<<1, 1, 0, stream>>>((const u16*)x, flag);
        pe_kernel<<<NTOT / 2, 256, 0, stream>>>(x, pos, pe_w, pe_b, h01, flag);
        for (int g = 0; g < NGRAPH; ++g) {
            int row0 = g * SEQ;
            mgemm_kernel<0,1><<<dim3(SEQ / 64, 3), 256, 0, stream>>>(
                h01, in_w, 0, in_b, nullptr, nullptr, nullptr, qkv_g, nullptr,
                QKVD, -1, row0, 0, flag);
            attn_lds_kernel<<<NHEAD * 16, 256, 0, stream>>>(qkv_g, ctx_g);
            mgemm_kernel<2,1><<<dim3(SEQ / 64, 1), 256, 0, stream>>>(
                ctx_g, out_w, 0, out_b, h01, ln1_g, ln1_b, h01, nullptr,
                DIM, DIM, 0, row0, flag);
        }
        for (int g = 0; g < NGRAPH; ++g) {
            int row0 = g * SEQ;
            mgemm_kernel<1,1><<<dim3(SEQ / 64, 4), 256, 0, stream>>>(
                h01, ff1_w, 0, ff1_b, nullptr, nullptr, nullptr, f1_g, nullptr,
                4 * DIM, -1, row0, 0, flag);
            mgemm_kernel<3,4><<<dim3(SEQ / 64, 1), 256, 0, stream>>>(
                f1_g, ff2_w, 0, ff2_b, h01, ln2_g, ln2_b, d_out, nullptr,
                DIM, 4 * DIM, 0, row0, flag);
        }
    }
}

// Round 9
// 172.884 us; speedup vs baseline: 1.1151x; 1.1151x over previous
//
#include <hip/hip_runtime.h>

typedef unsigned short u16;

#define NGRAPH 16
#define SEQ    1024
#define DIM    128
#define NHEAD  2
#define HDIM   64
#define KPOS   20
#define NTOT   (NGRAPH*SEQ)     // 16384
#define QKVD   (3*DIM)          // 384

// ---------- bf16 helpers ----------------------------------------------------
__device__ __forceinline__ float bf2f(u16 u) {
    return __uint_as_float(((unsigned int)u) << 16);
}
__device__ __forceinline__ u16 f2bf(float f) {
    unsigned int u = __float_as_uint(f);
    u += 0x7fffu + ((u >> 16) & 1u);   // RNE
    return (u16)(u >> 16);
}

// ---------- DPP 16-lane reductions (VALU, keeps DS pipe free) --------------
template<int CTRL>
__device__ __forceinline__ float dpp_ror(float x) {
    return __int_as_float(__builtin_amdgcn_update_dpp(
        __float_as_int(x), __float_as_int(x), CTRL, 0xF, 0xF, true));
}
__device__ __forceinline__ float row16_max(float x) {
    x = fmaxf(x, dpp_ror<0x121>(x));
    x = fmaxf(x, dpp_ror<0x122>(x));
    x = fmaxf(x, dpp_ror<0x124>(x));
    x = fmaxf(x, dpp_ror<0x128>(x));
    return x;
}
__device__ __forceinline__ float row16_sum(float x) {
    x += dpp_ror<0x121>(x);
    x += dpp_ror<0x122>(x);
    x += dpp_ror<0x124>(x);
    x += dpp_ror<0x128>(x);
    return x;
}

// ---------- dtype-adaptive input loads (fbf=1: bf16, fbf=0: f32) -----------
__device__ __forceinline__ float ld1(const void* p, int fbf, size_t i) {
    return fbf ? bf2f(((const u16*)p)[i]) : ((const float*)p)[i];
}
__device__ __forceinline__ float4 ldw8(const void* W, int fbf, size_t i) {
    if (fbf) return *(const float4*)((const u16*)W + i);
    const float* q = (const float*)W + i;
    float4 a = *(const float4*)q, b = *(const float4*)(q + 4);
    float4 r;
    u16* d = (u16*)&r;
    d[0]=f2bf(a.x); d[1]=f2bf(a.y); d[2]=f2bf(a.z); d[3]=f2bf(a.w);
    d[4]=f2bf(b.x); d[5]=f2bf(b.y); d[6]=f2bf(b.z); d[7]=f2bf(b.w);
    return r;
}

typedef __attribute__((ext_vector_type(8))) short bf16x8;
typedef __attribute__((ext_vector_type(4))) float f32x4;

// ---------- direct global->LDS (width 16), per-lane global addr ------------
__device__ __forceinline__ void gload16(const u16* g, u16* l) {
    __builtin_amdgcn_global_load_lds(
        (const __attribute__((address_space(1))) unsigned int*)(g),
        (__attribute__((address_space(3))) unsigned int*)(l), 16, 0, 0);
}
#define VMCNT0() asm volatile("s_waitcnt vmcnt(0)" ::: "memory")

// ---------- dtype detect ----------------------------------------------------
__device__ __forceinline__ int detect_bf16(const u16* x) {
    int ok = 1;
    for (int i = 0; i < 256; i += 2) {
        unsigned e = (x[i] >> 7) & 0xFF;
        if (e < 60u || e > 180u) ok = 0;
    }
    return ok;
}
__global__ void detect_kernel(const u16* __restrict__ x, int* __restrict__ flag) {
    if (threadIdx.x == 0 && blockIdx.x == 0) *flag = detect_bf16(x);
}

// ---------- K0: weight conversion to bf16 (+ self-detect, writes flag) -----
__global__ __launch_bounds__(256)
void wconv_kernel(const void* __restrict__ in_w, const void* __restrict__ out_w,
                  const void* __restrict__ ff1_w, const void* __restrict__ ff2_w,
                  const u16* __restrict__ x,
                  u16* __restrict__ wbf, int* __restrict__ flag) {
    __shared__ int fsh;
    if (threadIdx.x == 0) {
        int ok = detect_bf16(x);
        fsh = ok;
        if (blockIdx.x == 0) *flag = ok;
    }
    __syncthreads();
    int fbf = fsh;
    int i8 = (blockIdx.x * 256 + threadIdx.x) * 8;
    const void* src; int off;
    if      (i8 <  49152) { src = in_w;  off = i8; }
    else if (i8 <  65536) { src = out_w; off = i8 - 49152; }
    else if (i8 < 131072) { src = ff1_w; off = i8 - 65536; }
    else                  { src = ff2_w; off = i8 - 131072; }
    *(float4*)&wbf[i8] = ldw8(src, fbf, off);
}

// ---------- K1 (fallback only): pe ------------------------------------------
__global__ __launch_bounds__(256)
void pe_kernel(const void* __restrict__ x, const void* __restrict__ pos,
               const void* __restrict__ pe_w, const void* __restrict__ pe_b,
               u16* __restrict__ h0, const int* __restrict__ flag) {
    int fbf = *flag;
    __shared__ float wsh[DIM][KPOS + 1];
    int t = threadIdx.x;
    for (int i = t; i < DIM * KPOS; i += 256)
        wsh[i / KPOS][i % KPOS] = ld1(pe_w, fbf, i);
    __syncthreads();
    int row = blockIdx.x * 2 + (t >> 7), d = t & 127;
    float acc = 0.f;
#pragma unroll
    for (int k = 0; k < KPOS; ++k)
        acc += ld1(pos, fbf, (size_t)row * KPOS + k) * wsh[d][k];
    int rs = fbf ? 128 : 256;
    h0[(size_t)row * rs + d] =
        f2bf(ld1(x, fbf, (size_t)row * DIM + d) + acc + ld1(pe_b, fbf, d));
}

// ===========================================================================
// K2q (batched): FUSED pe + QKV GEMM (unchanged from R7).
// ===========================================================================
__global__ __launch_bounds__(256)
void qkvpe_kernel(const void* __restrict__ x, const void* __restrict__ pos,
                  const void* __restrict__ pe_w, const void* __restrict__ pe_b,
                  const u16* __restrict__ W, const void* __restrict__ bias,
                  u16* __restrict__ h0, u16* __restrict__ qkv,
                  u16* __restrict__ vt, const int* __restrict__ flag) {
    int fbf = *flag;
    int rs  = fbf ? 128 : 256;
    __shared__ __align__(16) u16 Ash[64][128];
    __shared__ __align__(16) u16 Wsh[2][128][128];
    __shared__ float wsh[DIM][KPOS + 1];
    __shared__ float possh[64][KPOS + 1];
    int t = threadIdx.x;
    int w = t >> 6, lane = t & 63, l16 = lane & 15, quad = lane >> 4;
    int n0 = blockIdx.x * 64;
    int xr = (l16 & 7) << 3;

    // issue W tile 0 early (flies under pe)
#pragma unroll
    for (int i = 0; i < 8; ++i) {
        int r = w * 4 + i * 16 + (lane >> 4);
        int s = (lane & 15) ^ (r & 7);
        gload16(&W[(size_t)r * 128 + s * 8], &Wsh[0][w * 4 + i * 16][0]);
    }
    for (int i = t; i < DIM * KPOS; i += 256)
        wsh[i / KPOS][i % KPOS] = ld1(pe_w, fbf, i);
    for (int i = t; i < 64 * KPOS; i += 256)
        possh[i / KPOS][i % KPOS] =
            ld1(pos, fbf, (size_t)(n0 + i / KPOS) * KPOS + i % KPOS);
    asm volatile("s_waitcnt lgkmcnt(0)" ::: "memory");
    __builtin_amdgcn_s_barrier();

    // pe: h0 tile -> Ash (XOR layout) + global (slot layout)
#pragma unroll
    for (int u = 0; u < 4; ++u) {
        int gu = t + u * 256;
        int r = gu >> 4, g = gu & 15;
        float4 hv;
        u16* hp = (u16*)&hv;
#pragma unroll
        for (int j = 0; j < 8; ++j) {
            int d = g * 8 + j;
            float a = ld1(x, fbf, (size_t)(n0 + r) * DIM + d) + ld1(pe_b, fbf, d);
#pragma unroll
            for (int k = 0; k < KPOS; ++k) a += possh[r][k] * wsh[d][k];
            hp[j] = f2bf(a);
        }
        *(float4*)&Ash[r][(g ^ (r & 7)) * 8] = hv;
        *(float4*)&h0[(size_t)(n0 + r) * rs + g * 8] = hv;
    }
    asm volatile("s_waitcnt lgkmcnt(0)" ::: "memory");
    __builtin_amdgcn_s_barrier();

#pragma unroll
    for (int m = 0; m < 3; ++m) {
        int m0 = m * 128;
        if (m < 2) {       // prefetch next W tile into other buffer
#pragma unroll
            for (int i = 0; i < 8; ++i) {
                int r = w * 4 + i * 16 + (lane >> 4);
                int s = (lane & 15) ^ (r & 7);
                gload16(&W[(size_t)(m0 + 128 + r) * 128 + s * 8],
                        &Wsh[(m + 1) & 1][w * 4 + i * 16][0]);
            }
            asm volatile("s_waitcnt vmcnt(8)" ::: "memory");
        } else {
            asm volatile("s_waitcnt vmcnt(0)" ::: "memory");
        }
        __builtin_amdgcn_s_barrier();
        f32x4 acc[8] = {};
        __builtin_amdgcn_s_setprio(1);
#pragma unroll
        for (int kk = 0; kk < 4; ++kk) {
            bf16x8 af = *(const bf16x8*)&Ash[w * 16 + l16][(kk * 32 + quad * 8) ^ xr];
#pragma unroll
            for (int s = 0; s < 8; ++s) {
                bf16x8 bf = *(const bf16x8*)&Wsh[m & 1][s * 16 + l16][(kk * 32 + quad * 8) ^ xr];
                acc[s] = __builtin_amdgcn_mfma_f32_16x16x32_bf16(af, bf, acc[s], 0, 0, 0);
            }
        }
        __builtin_amdgcn_s_setprio(0);
        float bb[8];
#pragma unroll
        for (int s = 0; s < 8; ++s) bb[s] = ld1(bias, fbf, m0 + s * 16 + l16);
#pragma unroll
        for (int r = 0; r < 4; ++r) {
            int lr = w * 16 + quad * 4 + r;
            if (m == 2) {          // V: store transposed vt[(b*128+d)*SEQ + n]
                int n = n0 + lr;
                int bg = n >> 10, nl = n & 1023;
#pragma unroll
                for (int s = 0; s < 8; ++s)
                    vt[((size_t)(bg * 128) + s * 16 + l16) * SEQ + nl] =
                        f2bf(acc[s][r] + bb[s]);
            } else {
#pragma unroll
                for (int s = 0; s < 8; ++s)
                    qkv[(size_t)(n0 + lr) * QKVD + m0 + s * 16 + l16] =
                        f2bf(acc[s][r] + bb[s]);
            }
        }
        if (m < 2) __builtin_amdgcn_s_barrier();   // Wsh reuse guard
    }
}

// ===========================================================================
// K3 (batched): LDS flash attention, gload_lds K/V double-buffer
// (restored from R7 -- R8's head-serialized fusion halved parallel width
// and regressed; this keeps 512-block width).
// ===========================================================================
__global__ __launch_bounds__(256)
void attn2_kernel(const u16* __restrict__ qkv, const u16* __restrict__ vtp,
                  u16* __restrict__ ctx) {
    __shared__ __align__(16) u16 Qsh[64][72];
    __shared__ __align__(16) u16 Ksh[2][64][64];
    __shared__ __align__(16) u16 Vsh[2][64][64];
    __shared__ u16 Psh[64][72];
    int t    = threadIdx.x;
    int w    = t >> 6;
    int lane = t & 63;
    int l16  = lane & 15;
    int quad = lane >> 4;
    int xr   = (l16 & 7) << 3;
    int L = blockIdx.x;
    int ngh = gridDim.x >> 4;
    int qt, gh;
    if (ngh >= 8) {
        int g8 = L & 7; int rest = L >> 3;
        qt = rest & 15; gh = (rest >> 4) * 8 + g8;
    } else {
        qt = L & 15; gh = L >> 4;
    }
    int b = gh >> 1, h = gh & 1;

#pragma unroll
    for (int i = 0; i < 2; ++i) {
        int idx = t + i * 256;
        int r = idx >> 3, d8 = (idx & 7) * 8;
        size_t n = (size_t)b * SEQ + qt * 64 + r;
        float4 qv = *(const float4*)&qkv[n * QKVD + h * HDIM + d8];
        u16* qp = (u16*)&qv;
#pragma unroll
        for (int j = 0; j < 8; ++j) qp[j] = f2bf(bf2f(qp[j]) * 0.125f);
        *(float4*)&Qsh[r][d8] = qv;
    }

    const u16* kbase = qkv + (size_t)b * SEQ * QKVD + DIM + h * HDIM;
    const u16* vbase = vtp + (size_t)((b * 2 + h) * 64) * SEQ;

    auto stageKV = [&](int kt, int bf) {
#pragma unroll
        for (int i = 0; i < 2; ++i) {
            int r = w * 8 + i * 32 + (lane >> 3);
            int s = (lane & 7) ^ (r & 7);
            gload16(&kbase[(size_t)(kt * 64 + r) * QKVD + s * 8],
                    &Ksh[bf][w * 8 + i * 32][0]);
        }
#pragma unroll
        for (int i = 0; i < 2; ++i) {
            int r = w * 8 + i * 32 + (lane >> 3);
            int s = (lane & 7) ^ (r & 7);
            gload16(&vbase[(size_t)r * SEQ + kt * 64 + s * 8],
                    &Vsh[bf][w * 8 + i * 32][0]);
        }
    };

    stageKV(0, 0);
    VMCNT0();
    __syncthreads();
    bf16x8 qa0 = *(const bf16x8*)&Qsh[w * 16 + l16][quad * 8];
    bf16x8 qa1 = *(const bf16x8*)&Qsh[w * 16 + l16][32 + quad * 8];

    f32x4 o[4] = {};
    float mrow[4] = {-1e30f, -1e30f, -1e30f, -1e30f};
    float lrow[4] = {};

#pragma unroll 1
    for (int kt = 0; kt < SEQ / 64; ++kt) {
        int cur = kt & 1;
        if (kt + 1 < SEQ / 64) stageKV(kt + 1, cur ^ 1);

        float sc[4][4];
        __builtin_amdgcn_s_setprio(1);
#pragma unroll
        for (int c = 0; c < 4; ++c) {
            bf16x8 kb0 = *(const bf16x8*)&Ksh[cur][c * 16 + l16][(quad * 8) ^ xr];
            bf16x8 kb1 = *(const bf16x8*)&Ksh[cur][c * 16 + l16][(32 + quad * 8) ^ xr];
            f32x4 s = {};
            s = __builtin_amdgcn_mfma_f32_16x16x32_bf16(qa0, kb0, s, 0, 0, 0);
            s = __builtin_amdgcn_mfma_f32_16x16x32_bf16(qa1, kb1, s, 0, 0, 0);
#pragma unroll
            for (int r = 0; r < 4; ++r) sc[c][r] = s[r];
        }
        __builtin_amdgcn_s_setprio(0);
        float alpha[4];
#pragma unroll
        for (int r = 0; r < 4; ++r) {
            float mx = fmaxf(fmaxf(sc[0][r], sc[1][r]), fmaxf(sc[2][r], sc[3][r]));
            mx = row16_max(mx);
            float mnew = fmaxf(mrow[r], mx);
            alpha[r] = __expf(mrow[r] - mnew);
            mrow[r] = mnew;
            float sum = 0.f;
#pragma unroll
            for (int c = 0; c < 4; ++c) {
                float p = __expf(sc[c][r] - mnew);
                sc[c][r] = p;
                sum += p;
            }
            sum = row16_sum(sum);
            lrow[r] = lrow[r] * alpha[r] + sum;
        }
#pragma unroll
        for (int c = 0; c < 4; ++c)
#pragma unroll
            for (int r = 0; r < 4; ++r)
                Psh[w * 16 + quad * 4 + r][c * 16 + l16] = f2bf(sc[c][r]);
#pragma unroll
        for (int dt = 0; dt < 4; ++dt)
#pragma unroll
            for (int r = 0; r < 4; ++r) o[dt][r] *= alpha[r];
        bf16x8 pa0 = *(const bf16x8*)&Psh[w * 16 + l16][quad * 8];
        bf16x8 pa1 = *(const bf16x8*)&Psh[w * 16 + l16][32 + quad * 8];
        __builtin_amdgcn_s_setprio(1);
#pragma unroll
        for (int dt = 0; dt < 4; ++dt) {
            bf16x8 vb0 = *(const bf16x8*)&Vsh[cur][dt * 16 + l16][(quad * 8) ^ xr];
            bf16x8 vb1 = *(const bf16x8*)&Vsh[cur][dt * 16 + l16][(32 + quad * 8) ^ xr];
            o[dt] = __builtin_amdgcn_mfma_f32_16x16x32_bf16(pa0, vb0, o[dt], 0, 0, 0);
            o[dt] = __builtin_amdgcn_mfma_f32_16x16x32_bf16(pa1, vb1, o[dt], 0, 0, 0);
        }
        __builtin_amdgcn_s_setprio(0);
        if (kt + 1 < SEQ / 64) {
            VMCNT0();
            __syncthreads();
        }
    }
#pragma unroll
    for (int r = 0; r < 4; ++r) {
        float inv = 1.f / lrow[r];
        size_t n = (size_t)b * SEQ + qt * 64 + w * 16 + quad * 4 + r;
#pragma unroll
        for (int dt = 0; dt < 4; ++dt)
            ctx[n * DIM + h * HDIM + dt * 16 + l16] = f2bf(o[dt][r] * inv);
    }
}

// ===========================================================================
// K4 (batched): FUSED out-proj+LN1 + FFN + LN2.
// R8 lesson: fusing INTO attention halved its parallel width (regressed).
// This boundary preserves width: out-proj's output tile (h1 rows n0..n0+63)
// IS the ffn block's A-tile, both phases 256-block. Phase 0 stages ctx-tile
// + out_w overlaid on the not-yet-used F1sh region (vmcnt(8) leaves W1c0 in
// flight), GEMM K=128 + h0-resid + LN1 -> h1 written to Ash in the proven
// F1sh XOR write/read layout. Then the unchanged R7 ffn pipeline. Deletes
// one dispatch + the 8MB h1 round-trip. h0 (in d_out) is read and later
// overwritten by the final output -- block-local rows, no hazard.
// LDS 144KB (same as R7 ffn).
// ===========================================================================
__global__ __launch_bounds__(256)
void outffn_kernel(const u16* __restrict__ ctx, const u16* __restrict__ Wout,
                   const void* __restrict__ out_b,
                   const void* __restrict__ l1g, const void* __restrict__ l1b,
                   const u16* __restrict__ h0,
                   const u16* __restrict__ W1, const u16* __restrict__ W2,
                   const void* __restrict__ b1, const void* __restrict__ b2,
                   const void* __restrict__ l2g, const void* __restrict__ l2b,
                   void* __restrict__ outp, const int* __restrict__ flag) {
    int fbf = *flag;
    int rs  = fbf ? 128 : 256;
    __shared__ __align__(16) u16 Ash[64][128];         // h1 tile (XOR layout)
    __shared__ __align__(16) u16 Wsh[2][128][128];     // weight double buffer
    __shared__ __align__(16) u16 F1sh[4][64][128];     // f1; phase-0 overlay below
    u16 (*CtxSh)[128]  = (u16(*)[128])&F1sh[0][0][0];  // 64 rows  (16KB)
    u16 (*WoutSh)[128] = (u16(*)[128])&F1sh[2][0][0];  // 128 rows (32KB)
    int t = threadIdx.x;
    int w = t >> 6, lane = t & 63, l16 = lane & 15, quad = lane >> 4;
    int n0 = blockIdx.x * 64;
    int xr = (l16 & 7) << 3;

    // issue: ctx tile (4/thr), Wout (8/thr), W1 chunk0 (8/thr)
#pragma unroll
    for (int i = 0; i < 4; ++i) {
        int r = w * 4 + i * 16 + (lane >> 4);
        int s = (lane & 15) ^ (r & 7);
        gload16(&ctx[(size_t)(n0 + r) * DIM + s * 8], &CtxSh[w * 4 + i * 16][0]);
    }
#pragma unroll
    for (int i = 0; i < 8; ++i) {
        int r = w * 4 + i * 16 + (lane >> 4);
        int s = (lane & 15) ^ (r & 7);
        gload16(&Wout[(size_t)r * 128 + s * 8], &WoutSh[w * 4 + i * 16][0]);
    }
#pragma unroll
    for (int i = 0; i < 8; ++i) {
        int r = w * 4 + i * 16 + (lane >> 4);
        int s = (lane & 15) ^ (r & 7);
        gload16(&W1[(size_t)r * 128 + s * 8], &Wsh[0][w * 4 + i * 16][0]);
    }
    asm volatile("s_waitcnt vmcnt(8)" ::: "memory");   // ctx+Wout landed; W1c0 in flight
    __builtin_amdgcn_s_barrier();

    // ---- GEMM0: h1 = ctx @ out_w^T (K=128) + bias + h0-resid + LN1 -> Ash ----
    {
        f32x4 acc[8] = {};
        __builtin_amdgcn_s_setprio(1);
#pragma unroll
        for (int kk = 0; kk < 4; ++kk) {
            bf16x8 af = *(const bf16x8*)&CtxSh[w * 16 + l16][(kk * 32 + quad * 8) ^ xr];
#pragma unroll
            for (int s = 0; s < 8; ++s) {
                bf16x8 bf = *(const bf16x8*)&WoutSh[s * 16 + l16][(kk * 32 + quad * 8) ^ xr];
                acc[s] = __builtin_amdgcn_mfma_f32_16x16x32_bf16(af, bf, acc[s], 0, 0, 0);
            }
        }
        __builtin_amdgcn_s_setprio(0);
        float bb[8], gg[8], be[8];
#pragma unroll
        for (int s = 0; s < 8; ++s) {
            bb[s] = ld1(out_b, fbf, s * 16 + l16);
            gg[s] = ld1(l1g, fbf, s * 16 + l16);
            be[s] = ld1(l1b, fbf, s * 16 + l16);
        }
#pragma unroll
        for (int r = 0; r < 4; ++r) {
            int lr = w * 16 + quad * 4 + r;
            size_t rg = (size_t)(n0 + lr);
            float v[8];
#pragma unroll
            for (int s = 0; s < 8; ++s)
                v[s] = acc[s][r] + bb[s] + bf2f(h0[rg * rs + s * 16 + l16]);
            float sm = 0.f, sq = 0.f;
#pragma unroll
            for (int s = 0; s < 8; ++s) { sm += v[s]; sq += v[s] * v[s]; }
            sm = row16_sum(sm);
            sq = row16_sum(sq);
            float mu  = sm * (1.f / DIM);
            float var = fmaxf(sq * (1.f / DIM) - mu * mu, 0.f);
            float rsq = rsqrtf(var + 1e-5f);
#pragma unroll
            for (int s = 0; s < 8; ++s) {
                int e = s * 16 + l16;
                int g = e >> 3;
                Ash[lr][((g ^ (lr & 7)) << 3) + (e & 7)] =
                    f2bf((v[s] - mu) * rsq * gg[s] + be[s]);
            }
        }
        asm volatile("s_waitcnt lgkmcnt(0)" ::: "memory");
        __builtin_amdgcn_s_barrier();   // Ash ready; CtxSh/WoutSh consumed
    }

    // ---- GEMM1: 4 column tiles of ff1 -> F1sh (relu+bias, XOR layout) ----
#pragma unroll
    for (int m = 0; m < 4; ++m) {
#pragma unroll
        for (int i = 0; i < 8; ++i) {
            int r = w * 4 + i * 16 + (lane >> 4);
            int s = (lane & 15) ^ (r & 7);
            if (m < 3)
                gload16(&W1[(size_t)((m + 1) * 128 + r) * 128 + s * 8],
                        &Wsh[(m + 1) & 1][w * 4 + i * 16][0]);
            else
                gload16(&W2[(size_t)r * 512 + s * 8],
                        &Wsh[0][w * 4 + i * 16][0]);
        }
        asm volatile("s_waitcnt vmcnt(8)" ::: "memory");
        __builtin_amdgcn_s_barrier();
        f32x4 acc[8] = {};
        __builtin_amdgcn_s_setprio(1);
#pragma unroll
        for (int kk = 0; kk < 4; ++kk) {
            bf16x8 af = *(const bf16x8*)&Ash[w * 16 + l16][(kk * 32 + quad * 8) ^ xr];
#pragma unroll
            for (int s = 0; s < 8; ++s) {
                bf16x8 bf = *(const bf16x8*)&Wsh[m & 1][s * 16 + l16][(kk * 32 + quad * 8) ^ xr];
                acc[s] = __builtin_amdgcn_mfma_f32_16x16x32_bf16(af, bf, acc[s], 0, 0, 0);
            }
        }
        __builtin_amdgcn_s_setprio(0);
        float bb[8];
#pragma unroll
        for (int s = 0; s < 8; ++s) bb[s] = ld1(b1, fbf, m * 128 + s * 16 + l16);
#pragma unroll
        for (int r = 0; r < 4; ++r) {
            int lr = w * 16 + quad * 4 + r;
#pragma unroll
            for (int s = 0; s < 8; ++s) {
                int g = s * 2 + (l16 >> 3);
                F1sh[m][lr][((g ^ (lr & 7)) << 3) + (l16 & 7)] =
                    f2bf(fmaxf(acc[s][r] + bb[s], 0.f));
            }
        }
        asm volatile("s_waitcnt lgkmcnt(0)" ::: "memory");
        __builtin_amdgcn_s_barrier();
    }

    // ---- GEMM2: out = f1 @ ff2^T, K=512 in 4 LDS chunks ----
    f32x4 acc2[8] = {};
#pragma unroll
    for (int c = 0; c < 4; ++c) {
        if (c < 3) {
#pragma unroll
            for (int i = 0; i < 8; ++i) {
                int r = w * 4 + i * 16 + (lane >> 4);
                int s = (lane & 15) ^ (r & 7);
                gload16(&W2[(size_t)r * 512 + (c + 1) * 128 + s * 8],
                        &Wsh[(c + 1) & 1][w * 4 + i * 16][0]);
            }
            asm volatile("s_waitcnt vmcnt(8)" ::: "memory");
        } else {
            asm volatile("s_waitcnt vmcnt(0)" ::: "memory");
        }
        __builtin_amdgcn_s_barrier();
        __builtin_amdgcn_s_setprio(1);
#pragma unroll
        for (int kk = 0; kk < 4; ++kk) {
            bf16x8 af = *(const bf16x8*)&F1sh[c][w * 16 + l16][(kk * 32 + quad * 8) ^ xr];
#pragma unroll
            for (int s = 0; s < 8; ++s) {
                bf16x8 bf = *(const bf16x8*)&Wsh[c & 1][s * 16 + l16][(kk * 32 + quad * 8) ^ xr];
                acc2[s] = __builtin_amdgcn_mfma_f32_16x16x32_bf16(af, bf, acc2[s], 0, 0, 0);
            }
        }
        __builtin_amdgcn_s_setprio(0);
        if (c < 3) __builtin_amdgcn_s_barrier();
    }

    // ---- LN2 epilogue: +b2 +resid(h1 from Ash) -> final out ----
    float bb[8], gg[8], be[8];
#pragma unroll
    for (int s = 0; s < 8; ++s) {
        bb[s] = ld1(b2, fbf, s * 16 + l16);
        gg[s] = ld1(l2g, fbf, s * 16 + l16);
        be[s] = ld1(l2b, fbf, s * 16 + l16);
    }
#pragma unroll
    for (int r = 0; r < 4; ++r) {
        int lr = w * 16 + quad * 4 + r;
        size_t rg = (size_t)(n0 + lr);
        float v[8];
#pragma unroll
        for (int s = 0; s < 8; ++s) {
            int g = s * 2 + (l16 >> 3);
            float resid = bf2f(Ash[lr][((g ^ (lr & 7)) << 3) + (l16 & 7)]);
            v[s] = acc2[s][r] + bb[s] + resid;
        }
        float sm = 0.f, sq = 0.f;
#pragma unroll
        for (int s = 0; s < 8; ++s) { sm += v[s]; sq += v[s] * v[s]; }
        sm = row16_sum(sm);
        sq = row16_sum(sq);
        float mu  = sm * (1.f / DIM);
        float var = fmaxf(sq * (1.f / DIM) - mu * mu, 0.f);
        float rsq = rsqrtf(var + 1e-5f);
        if (fbf) {
            u16* o = (u16*)outp;
#pragma unroll
            for (int s = 0; s < 8; ++s)
                o[rg * 128 + s * 16 + l16] =
                    f2bf((v[s] - mu) * rsq * gg[s] + be[s]);
        } else {
            float* o = (float*)outp;
#pragma unroll
            for (int s = 0; s < 8; ++s)
                o[rg * 128 + s * 16 + l16] =
                    (v[s] - mu) * rsq * gg[s] + be[s];
        }
    }
}

// ============================================================================
//                 LEGACY KERNELS (per-graph fallback path)
// ============================================================================
template<int EPI, int NK>
__global__ __launch_bounds__(256)
void mgemm_kernel(const u16* __restrict__ A, const void* __restrict__ W,
                  int wbf16, const void* __restrict__ bias,
                  const u16* __restrict__ resid,
                  const void* __restrict__ lng, const void* __restrict__ lnb,
                  void* __restrict__ outp, u16* __restrict__ vt,
                  int Mtot, int AstrIn,
                  int arow0, int orow0, const int* __restrict__ flag) {
    const int K = NK * 128;
    int fbf  = *flag;
    int wfmt = wbf16 ? 1 : fbf;
    int rs   = fbf ? 128 : 256;
    int Astr = (AstrIn < 0) ? rs : AstrIn;
    __shared__ u16 Ash[64][136];
    __shared__ u16 Wsh[128][136];
    int t = threadIdx.x;
    int w = t >> 6, lane = t & 63, l16 = lane & 15, quad = lane >> 4;
    int n0 = blockIdx.x * 64;
    int m0 = blockIdx.y * 128;
    f32x4 acc[8] = {};
    float4 aR[4], wR[8];
#pragma unroll
    for (int i = 0; i < 4; ++i) {
        int idx = t + i * 256;
        int row = idx >> 4, k8 = (idx & 15) * 8;
        aR[i] = *(const float4*)&A[(size_t)(arow0 + n0 + row) * Astr + k8];
    }
#pragma unroll
    for (int i = 0; i < 8; ++i) {
        int idx = t + i * 256;
        int row = idx >> 4, k8 = (idx & 15) * 8;
        wR[i] = ldw8(W, wfmt, (size_t)(m0 + row) * K + k8);
    }
#pragma unroll 1
    for (int c = 0; c < NK; ++c) {
#pragma unroll
        for (int i = 0; i < 4; ++i) {
            int idx = t + i * 256;
            *(float4*)&Ash[idx >> 4][(idx & 15) * 8] = aR[i];
        }
#pragma unroll
        for (int i = 0; i < 8; ++i) {
            int idx = t + i * 256;
            *(float4*)&Wsh[idx >> 4][(idx & 15) * 8] = wR[i];
        }
        __syncthreads();
        if (c + 1 < NK) {
            int kc = (c + 1) * 128;
#pragma unroll
            for (int i = 0; i < 4; ++i) {
                int idx = t + i * 256;
                int row = idx >> 4, k8 = (idx & 15) * 8;
                aR[i] = *(const float4*)&A[(size_t)(arow0 + n0 + row) * Astr + kc + k8];
            }
#pragma unroll
            for (int i = 0; i < 8; ++i) {
                int idx = t + i * 256;
                int row = idx >> 4, k8 = (idx & 15) * 8;
                wR[i] = ldw8(W, wfmt, (size_t)(m0 + row) * K + kc + k8);
            }
        }
        __builtin_amdgcn_s_setprio(1);
#pragma unroll
        for (int kk = 0; kk < 4; ++kk) {
            bf16x8 af = *(const bf16x8*)&Ash[w * 16 + l16][kk * 32 + quad * 8];
#pragma unroll
            for (int s = 0; s < 8; ++s) {
                bf16x8 bf = *(const bf16x8*)&Wsh[s * 16 + l16][kk * 32 + quad * 8];
                acc[s] = __builtin_amdgcn_mfma_f32_16x16x32_bf16(af, bf, acc[s], 0, 0, 0);
            }
        }
        __builtin_amdgcn_s_setprio(0);
        if (c + 1 < NK) __syncthreads();
    }
    float bb[8];
#pragma unroll
    for (int s = 0; s < 8; ++s) bb[s] = ld1(bias, fbf, m0 + s * 16 + l16);
    float gg[8], be[8];
    if (EPI >= 2) {
#pragma unroll
        for (int s = 0; s < 8; ++s) {
            gg[s] = ld1(lng, fbf, s * 16 + l16);
            be[s] = ld1(lnb, fbf, s * 16 + l16);
        }
    }
#pragma unroll
    for (int r = 0; r < 4; ++r) {
        int lr = w * 16 + quad * 4 + r;
        float v[8];
#pragma unroll
        for (int s = 0; s < 8; ++s) {
            v[s] = acc[s][r] + bb[s];
            if (EPI == 1) v[s] = fmaxf(v[s], 0.f);
        }
        if (EPI <= 1) {
            u16* o = (u16*)outp;
#pragma unroll
            for (int s = 0; s < 8; ++s)
                o[(size_t)(n0 + lr) * Mtot + m0 + s * 16 + l16] = f2bf(v[s]);
        } else {
            size_t rg = (size_t)(orow0 + n0 + lr);
#pragma unroll
            for (int s = 0; s < 8; ++s)
                v[s] += bf2f(resid[rg * rs + s * 16 + l16]);
            float sm = 0.f, sq = 0.f;
#pragma unroll
            for (int s = 0; s < 8; ++s) { sm += v[s]; sq += v[s] * v[s]; }
            sm = row16_sum(sm);
            sq = row16_sum(sq);
            float mu  = sm * (1.f / DIM);
            float var = fmaxf(sq * (1.f / DIM) - mu * mu, 0.f);
            float rsq = rsqrtf(var + 1e-5f);
            if (EPI == 2) {
                u16* o = (u16*)outp;
#pragma unroll
                for (int s = 0; s < 8; ++s)
                    o[rg * rs + s * 16 + l16] =
                        f2bf((v[s] - mu) * rsq * gg[s] + be[s]);
            } else {
                if (fbf) {
                    u16* o = (u16*)outp;
#pragma unroll
                    for (int s = 0; s < 8; ++s)
                        o[rg * 128 + s * 16 + l16] =
                            f2bf((v[s] - mu) * rsq * gg[s] + be[s]);
                } else {
                    float* o = (float*)outp;
#pragma unroll
                    for (int s = 0; s < 8; ++s)
                        o[rg * 128 + s * 16 + l16] =
                            (v[s] - mu) * rsq * gg[s] + be[s];
                }
            }
        }
    }
}

__global__ __launch_bounds__(256)
void attn_lds_kernel(const u16* __restrict__ qkv, u16* __restrict__ ctx) {
    __shared__ u16 Qsh[64][72];
    __shared__ u16 Ksh[64][72];
    __shared__ u16 VshT[64][72];
    __shared__ u16 Psh[64][72];
    int t    = threadIdx.x;
    int w    = t >> 6;
    int lane = t & 63;
    int l16  = lane & 15;
    int quad = lane >> 4;
    int L = blockIdx.x;
    int qt = L & 15, gh = L >> 4;
    int b = gh >> 1, h = gh & 1;

#pragma unroll
    for (int i = 0; i < 2; ++i) {
        int idx = t + i * 256;
        int r = idx >> 3, d8 = (idx & 7) * 8;
        size_t n = (size_t)b * SEQ + qt * 64 + r;
        float4 qv = *(const float4*)&qkv[n * QKVD + h * HDIM + d8];
        u16* qp = (u16*)&qv;
#pragma unroll
        for (int j = 0; j < 8; ++j) qp[j] = f2bf(bf2f(qp[j]) * 0.125f);
        *(float4*)&Qsh[r][d8] = qv;
    }
    int kr = t >> 3, kd8 = (t & 7) * 8;
    int vr = t & 63, vdb = (t >> 6) * 16;
    float4 kR[2], vR[2];
    {
        size_t nk0 = (size_t)b * SEQ + kr;
        kR[0] = *(const float4*)&qkv[nk0 * QKVD + DIM + h * HDIM + kd8];
        kR[1] = *(const float4*)&qkv[(nk0 + 32) * QKVD + DIM + h * HDIM + kd8];
        size_t nv0 = (size_t)b * SEQ + vr;
        vR[0] = *(const float4*)&qkv[nv0 * QKVD + 2 * DIM + h * HDIM + vdb];
        vR[1] = *(const float4*)&qkv[nv0 * QKVD + 2 * DIM + h * HDIM + vdb + 8];
    }
    __syncthreads();
    bf16x8 qa0 = *(const bf16x8*)&Qsh[w * 16 + l16][quad * 8];
    bf16x8 qa1 = *(const bf16x8*)&Qsh[w * 16 + l16][32 + quad * 8];

    f32x4 o[4] = {};
    float mrow[4] = {-1e30f, -1e30f, -1e30f, -1e30f};
    float lrow[4] = {};

#pragma unroll 1
    for (int kt = 0; kt < SEQ / 64; ++kt) {
        *(float4*)&Ksh[kr][kd8]      = kR[0];
        *(float4*)&Ksh[kr + 32][kd8] = kR[1];
        {
            const u16* pa = (const u16*)&vR[0];
            const u16* pb = (const u16*)&vR[1];
#pragma unroll
            for (int j = 0; j < 8; ++j) VshT[vdb + j][vr] = pa[j];
#pragma unroll
            for (int j = 0; j < 8; ++j) VshT[vdb + 8 + j][vr] = pb[j];
        }
        __syncthreads();
        if (kt + 1 < SEQ / 64) {
            size_t nk0 = (size_t)b * SEQ + (kt + 1) * 64 + kr;
            kR[0] = *(const float4*)&qkv[nk0 * QKVD + DIM + h * HDIM + kd8];
            kR[1] = *(const float4*)&qkv[(nk0 + 32) * QKVD + DIM + h * HDIM + kd8];
            size_t nv0 = (size_t)b * SEQ + (kt + 1) * 64 + vr;
            vR[0] = *(const float4*)&qkv[nv0 * QKVD + 2 * DIM + h * HDIM + vdb];
            vR[1] = *(const float4*)&qkv[nv0 * QKVD + 2 * DIM + h * HDIM + vdb + 8];
        }
        float sc[4][4];
        __builtin_amdgcn_s_setprio(1);
#pragma unroll
        for (int c = 0; c < 4; ++c) {
            bf16x8 kb0 = *(const bf16x8*)&Ksh[c * 16 + l16][quad * 8];
            bf16x8 kb1 = *(const bf16x8*)&Ksh[c * 16 + l16][32 + quad * 8];
            f32x4 s = {};
            s = __builtin_amdgcn_mfma_f32_16x16x32_bf16(qa0, kb0, s, 0, 0, 0);
            s = __builtin_amdgcn_mfma_f32_16x16x32_bf16(qa1, kb1, s, 0, 0, 0);
#pragma unroll
            for (int r = 0; r < 4; ++r) sc[c][r] = s[r];
        }
        __builtin_amdgcn_s_setprio(0);
        float alpha[4];
#pragma unroll
        for (int r = 0; r < 4; ++r) {
            float mx = fmaxf(fmaxf(sc[0][r], sc[1][r]), fmaxf(sc[2][r], sc[3][r]));
            mx = row16_max(mx);
            float mnew = fmaxf(mrow[r], mx);
            alpha[r] = __expf(mrow[r] - mnew);
            mrow[r] = mnew;
            float sum = 0.f;
#pragma unroll
            for (int c = 0; c < 4; ++c) {
                float p = __expf(sc[c][r] - mnew);
                sc[c][r] = p;
                sum += p;
            }
            sum = row16_sum(sum);
            lrow[r] = lrow[r] * alpha[r] + sum;
        }
#pragma unroll
        for (int c = 0; c < 4; ++c)
#pragma unroll
            for (int r = 0; r < 4; ++r)
                Psh[w * 16 + quad * 4 + r][c * 16 + l16] = f2bf(sc[c][r]);
#pragma unroll
        for (int dt = 0; dt < 4; ++dt)
#pragma unroll
            for (int r = 0; r < 4; ++r) o[dt][r] *= alpha[r];
        bf16x8 pa0 = *(const bf16x8*)&Psh[w * 16 + l16][quad * 8];
        bf16x8 pa1 = *(const bf16x8*)&Psh[w * 16 + l16][32 + quad * 8];
        __builtin_amdgcn_s_setprio(1);
#pragma unroll
        for (int dt = 0; dt < 4; ++dt) {
            bf16x8 vb0 = *(const bf16x8*)&VshT[dt * 16 + l16][quad * 8];
            bf16x8 vb1 = *(const bf16x8*)&VshT[dt * 16 + l16][32 + quad * 8];
            o[dt] = __builtin_amdgcn_mfma_f32_16x16x32_bf16(pa0, vb0, o[dt], 0, 0, 0);
            o[dt] = __builtin_amdgcn_mfma_f32_16x16x32_bf16(pa1, vb1, o[dt], 0, 0, 0);
        }
        __builtin_amdgcn_s_setprio(0);
        __syncthreads();
    }
#pragma unroll
    for (int r = 0; r < 4; ++r) {
        float inv = 1.f / lrow[r];
        size_t n = (size_t)b * SEQ + qt * 64 + w * 16 + quad * 4 + r;
#pragma unroll
        for (int dt = 0; dt < 4; ++dt)
            ctx[n * DIM + h * HDIM + dt * 16 + l16] = f2bf(o[dt][r] * inv);
    }
}

// ---------------------------------------------------------------------------
extern "C" void kernel_launch(void* const* d_in, const int* in_sizes, int n_in,
                              void* d_out, int out_size, void* d_ws, size_t ws_size,
                              hipStream_t stream) {
    const void* x     = d_in[0];
    const void* pos   = d_in[1];
    const void* pe_w  = d_in[2];
    const void* pe_b  = d_in[3];
    const void* in_w  = d_in[4];
    const void* in_b  = d_in[5];
    const void* out_w = d_in[6];
    const void* out_b = d_in[7];
    const void* ln1_g = d_in[8];
    const void* ln1_b = d_in[9];
    const void* ln2_g = d_in[10];
    const void* ln2_b = d_in[11];
    const void* ff1_w = d_in[12];
    const void* ff1_b = d_in[13];
    const void* ff2_w = d_in[14];
    const void* ff2_b = d_in[15];

    char* wsb  = (char*)d_ws;
    int*  flag = (int*)(wsb + ((ws_size - 4) & ~(size_t)3));
    u16*  h01  = (u16*)d_out;   // h0 bf16 in dtype-dependent row slots
    const size_t MB = 1024 * 1024;

    if (ws_size >= 21 * MB) {
        // batched path: qkv[0,12M), ctx[12,16M), vt[16,20M), wbf[20M,+384K)
        u16* qkv = (u16*)wsb;
        u16* ctx = (u16*)(wsb + 12 * MB);
        u16* vt  = (u16*)(wsb + 16 * MB);
        u16* wbf = (u16*)(wsb + 20 * MB);
        u16* wb_in  = wbf;
        u16* wb_out = wbf + 49152;
        u16* wb_ff1 = wbf + 65536;
        u16* wb_ff2 = wbf + 131072;

        wconv_kernel<<<96, 256, 0, stream>>>(in_w, out_w, ff1_w, ff2_w,
                                             (const u16*)x, wbf, flag);
        qkvpe_kernel<<<NTOT / 64, 256, 0, stream>>>(
            x, pos, pe_w, pe_b, wb_in, in_b, h01, qkv, vt, flag);
        attn2_kernel<<<NGRAPH * NHEAD * 16, 256, 0, stream>>>(qkv, vt, ctx);
        outffn_kernel<<<NTOT / 64, 256, 0, stream>>>(
            ctx, wb_out, out_b, ln1_g, ln1_b, h01,
            wb_ff1, wb_ff2, ff1_b, ff2_b, ln2_g, ln2_b, d_out, flag);
    } else {
        // per-graph path (legacy): qkv_g[0,768K), ctx_g[768K,1M); f1_g reuse
        u16* qkv_g = (u16*)wsb;
        u16* ctx_g = (u16*)(wsb + 768 * 1024);
        u16* f1_g  = (u16*)wsb;
        detect_kernel<<<1, 1, 0, stream>>>((const u16*)x, flag);
        pe_kernel<<<NTOT / 2, 256, 0, stream>>>(x, pos, pe_w, pe_b, h01, flag);
        for (int g = 0; g < NGRAPH; ++g) {
            int row0 = g * SEQ;
            mgemm_kernel<0,1><<<dim3(SEQ / 64, 3), 256, 0, stream>>>(
                h01, in_w, 0, in_b, nullptr, nullptr, nullptr, qkv_g, nullptr,
                QKVD, -1, row0, 0, flag);
            attn_lds_kernel<<<NHEAD * 16, 256, 0, stream>>>(qkv_g, ctx_g);
            mgemm_kernel<2,1><<<dim3(SEQ / 64, 1), 256, 0, stream>>>(
                ctx_g, out_w, 0, out_b, h01, ln1_g, ln1_b, h01, nullptr,
                DIM, DIM, 0, row0, flag);
        }
        for (int g = 0; g < NGRAPH; ++g) {
            int row0 = g * SEQ;
            mgemm_kernel<1,1><<<dim3(SEQ / 64, 4), 256, 0, stream>>>(
                h01, ff1_w, 0, ff1_b, nullptr, nullptr, nullptr, f1_g, nullptr,
                4 * DIM, -1, row0, 0, flag);
            mgemm_kernel<3,4><<<dim3(SEQ / 64, 1), 256, 0, stream>>>(
                f1_g, ff2_w, 0, ff2_b, h01, ln2_g, ln2_b, d_out, nullptr,
                DIM, 4 * DIM, 0, row0, flag);
        }
    }
}

// Round 10
// 169.729 us; speedup vs baseline: 1.1358x; 1.0186x over previous
//
#include <hip/hip_runtime.h>

typedef unsigned short u16;

#define NGRAPH 16
#define SEQ    1024
#define DIM    128
#define NHEAD  2
#define HDIM   64
#define KPOS   20
#define NTOT   (NGRAPH*SEQ)     // 16384
#define QKVD   (3*DIM)          // 384

// ---------- bf16 helpers ----------------------------------------------------
__device__ __forceinline__ float bf2f(u16 u) {
    return __uint_as_float(((unsigned int)u) << 16);
}
__device__ __forceinline__ u16 f2bf(float f) {
    unsigned int u = __float_as_uint(f);
    u += 0x7fffu + ((u >> 16) & 1u);   // RNE
    return (u16)(u >> 16);
}

// ---------- DPP 16-lane reductions (VALU, keeps DS pipe free) --------------
template<int CTRL>
__device__ __forceinline__ float dpp_ror(float x) {
    return __int_as_float(__builtin_amdgcn_update_dpp(
        __float_as_int(x), __float_as_int(x), CTRL, 0xF, 0xF, true));
}
__device__ __forceinline__ float row16_max(float x) {
    x = fmaxf(x, dpp_ror<0x121>(x));
    x = fmaxf(x, dpp_ror<0x122>(x));
    x = fmaxf(x, dpp_ror<0x124>(x));
    x = fmaxf(x, dpp_ror<0x128>(x));
    return x;
}
__device__ __forceinline__ float row16_sum(float x) {
    x += dpp_ror<0x121>(x);
    x += dpp_ror<0x122>(x);
    x += dpp_ror<0x124>(x);
    x += dpp_ror<0x128>(x);
    return x;
}

// ---------- dtype-adaptive input loads (fbf=1: bf16, fbf=0: f32) -----------
__device__ __forceinline__ float ld1(const void* p, int fbf, size_t i) {
    return fbf ? bf2f(((const u16*)p)[i]) : ((const float*)p)[i];
}
__device__ __forceinline__ float4 ldw8(const void* W, int fbf, size_t i) {
    if (fbf) return *(const float4*)((const u16*)W + i);
    const float* q = (const float*)W + i;
    float4 a = *(const float4*)q, b = *(const float4*)(q + 4);
    float4 r;
    u16* d = (u16*)&r;
    d[0]=f2bf(a.x); d[1]=f2bf(a.y); d[2]=f2bf(a.z); d[3]=f2bf(a.w);
    d[4]=f2bf(b.x); d[5]=f2bf(b.y); d[6]=f2bf(b.z); d[7]=f2bf(b.w);
    return r;
}
// vectorized 8-value load (float4-based), dtype-adaptive
__device__ __forceinline__ void ld8f(const void* p, int fbf, size_t i, float* o) {
    if (fbf) {
        float4 v = *(const float4*)((const u16*)p + i);
        const u16* q = (const u16*)&v;
#pragma unroll
        for (int j = 0; j < 8; ++j) o[j] = bf2f(q[j]);
    } else {
        float4 a = *(const float4*)((const float*)p + i);
        float4 b = *(const float4*)((const float*)p + i + 4);
        o[0]=a.x; o[1]=a.y; o[2]=a.z; o[3]=a.w;
        o[4]=b.x; o[5]=b.y; o[6]=b.z; o[7]=b.w;
    }
}

typedef __attribute__((ext_vector_type(8))) short bf16x8;
typedef __attribute__((ext_vector_type(4))) float f32x4;

// ---------- direct global->LDS (width 16), per-lane global addr ------------
__device__ __forceinline__ void gload16(const u16* g, u16* l) {
    __builtin_amdgcn_global_load_lds(
        (const __attribute__((address_space(1))) unsigned int*)(g),
        (__attribute__((address_space(3))) unsigned int*)(l), 16, 0, 0);
}
#define VMCNT0() asm volatile("s_waitcnt vmcnt(0)" ::: "memory")

// ---------- dtype detect ----------------------------------------------------
__device__ __forceinline__ int detect_bf16(const u16* x) {
    int ok = 1;
    for (int i = 0; i < 256; i += 2) {
        unsigned e = (x[i] >> 7) & 0xFF;
        if (e < 60u || e > 180u) ok = 0;
    }
    return ok;
}
__global__ void detect_kernel(const u16* __restrict__ x, int* __restrict__ flag) {
    if (threadIdx.x == 0 && blockIdx.x == 0) *flag = detect_bf16(x);
}

// ---------- K0: weight conversion to bf16 (+ self-detect, writes flag) -----
__global__ __launch_bounds__(256)
void wconv_kernel(const void* __restrict__ in_w, const void* __restrict__ out_w,
                  const void* __restrict__ ff1_w, const void* __restrict__ ff2_w,
                  const u16* __restrict__ x,
                  u16* __restrict__ wbf, int* __restrict__ flag) {
    __shared__ int fsh;
    if (threadIdx.x == 0) {
        int ok = detect_bf16(x);
        fsh = ok;
        if (blockIdx.x == 0) *flag = ok;
    }
    __syncthreads();
    int fbf = fsh;
    int i8 = (blockIdx.x * 256 + threadIdx.x) * 8;
    const void* src; int off;
    if      (i8 <  49152) { src = in_w;  off = i8; }
    else if (i8 <  65536) { src = out_w; off = i8 - 49152; }
    else if (i8 < 131072) { src = ff1_w; off = i8 - 65536; }
    else                  { src = ff2_w; off = i8 - 131072; }
    *(float4*)&wbf[i8] = ldw8(src, fbf, off);
}

// ---------- K1 (fallback only): pe ------------------------------------------
__global__ __launch_bounds__(256)
void pe_kernel(const void* __restrict__ x, const void* __restrict__ pos,
               const void* __restrict__ pe_w, const void* __restrict__ pe_b,
               u16* __restrict__ h0, const int* __restrict__ flag) {
    int fbf = *flag;
    __shared__ float wsh[DIM][KPOS + 1];
    int t = threadIdx.x;
    for (int i = t; i < DIM * KPOS; i += 256)
        wsh[i / KPOS][i % KPOS] = ld1(pe_w, fbf, i);
    __syncthreads();
    int row = blockIdx.x * 2 + (t >> 7), d = t & 127;
    float acc = 0.f;
#pragma unroll
    for (int k = 0; k < KPOS; ++k)
        acc += ld1(pos, fbf, (size_t)row * KPOS + k) * wsh[d][k];
    int rs = fbf ? 128 : 256;
    h0[(size_t)row * rs + d] =
        f2bf(ld1(x, fbf, (size_t)row * DIM + d) + acc + ld1(pe_b, fbf, d));
}

// ===========================================================================
// K2q (batched): FUSED pe + QKV GEMM.
// R10: pe phase restructured k-outer -- per thread 240 LDS reads (was 1280:
// 640 MACs x 2 scalar reads) by hoisting wk[8]/pk[4] per k; x/pe_b loads
// vectorized float4 (were 32+8 scalar ld1). Same output mapping.
// ===========================================================================
__global__ __launch_bounds__(256)
void qkvpe_kernel(const void* __restrict__ x, const void* __restrict__ pos,
                  const void* __restrict__ pe_w, const void* __restrict__ pe_b,
                  const u16* __restrict__ W, const void* __restrict__ bias,
                  u16* __restrict__ h0, u16* __restrict__ qkv,
                  u16* __restrict__ vt, const int* __restrict__ flag) {
    int fbf = *flag;
    int rs  = fbf ? 128 : 256;
    __shared__ __align__(16) u16 Ash[64][128];
    __shared__ __align__(16) u16 Wsh[2][128][128];
    __shared__ float wsh[DIM][KPOS + 1];
    __shared__ float possh[64][KPOS + 1];
    int t = threadIdx.x;
    int w = t >> 6, lane = t & 63, l16 = lane & 15, quad = lane >> 4;
    int n0 = blockIdx.x * 64;
    int xr = (l16 & 7) << 3;

    // issue W tile 0 early (flies under pe)
#pragma unroll
    for (int i = 0; i < 8; ++i) {
        int r = w * 4 + i * 16 + (lane >> 4);
        int s = (lane & 15) ^ (r & 7);
        gload16(&W[(size_t)r * 128 + s * 8], &Wsh[0][w * 4 + i * 16][0]);
    }
    for (int i = t; i < DIM * KPOS; i += 256)
        wsh[i / KPOS][i % KPOS] = ld1(pe_w, fbf, i);
    for (int i = t; i < 64 * KPOS; i += 256)
        possh[i / KPOS][i % KPOS] =
            ld1(pos, fbf, (size_t)(n0 + i / KPOS) * KPOS + i % KPOS);
    asm volatile("s_waitcnt lgkmcnt(0)" ::: "memory");
    __builtin_amdgcn_s_barrier();

    // pe: h0 tile -> Ash (XOR layout) + global (slot layout). k-outer loop.
    {
        int g  = t & 15;           // column-group (constant across u)
        int r0 = t >> 4;           // base row
        float acc[4][8];
        float pb[8];
        ld8f(pe_b, fbf, g * 8, pb);
#pragma unroll
        for (int u = 0; u < 4; ++u) {
            int r = r0 + u * 16;
            float xv[8];
            ld8f(x, fbf, (size_t)(n0 + r) * DIM + g * 8, xv);
#pragma unroll
            for (int j = 0; j < 8; ++j) acc[u][j] = xv[j] + pb[j];
        }
#pragma unroll
        for (int k = 0; k < KPOS; ++k) {
            float wk[8], pk[4];
#pragma unroll
            for (int j = 0; j < 8; ++j) wk[j] = wsh[g * 8 + j][k];
#pragma unroll
            for (int u = 0; u < 4; ++u) pk[u] = possh[r0 + u * 16][k];
#pragma unroll
            for (int u = 0; u < 4; ++u)
#pragma unroll
                for (int j = 0; j < 8; ++j) acc[u][j] += pk[u] * wk[j];
        }
#pragma unroll
        for (int u = 0; u < 4; ++u) {
            int r = r0 + u * 16;
            float4 hv; u16* hp = (u16*)&hv;
#pragma unroll
            for (int j = 0; j < 8; ++j) hp[j] = f2bf(acc[u][j]);
            *(float4*)&Ash[r][(g ^ (r & 7)) * 8] = hv;
            *(float4*)&h0[(size_t)(n0 + r) * rs + g * 8] = hv;
        }
    }
    asm volatile("s_waitcnt lgkmcnt(0)" ::: "memory");
    __builtin_amdgcn_s_barrier();

#pragma unroll
    for (int m = 0; m < 3; ++m) {
        int m0 = m * 128;
        if (m < 2) {       // prefetch next W tile into other buffer
#pragma unroll
            for (int i = 0; i < 8; ++i) {
                int r = w * 4 + i * 16 + (lane >> 4);
                int s = (lane & 15) ^ (r & 7);
                gload16(&W[(size_t)(m0 + 128 + r) * 128 + s * 8],
                        &Wsh[(m + 1) & 1][w * 4 + i * 16][0]);
            }
            asm volatile("s_waitcnt vmcnt(8)" ::: "memory");
        } else {
            asm volatile("s_waitcnt vmcnt(0)" ::: "memory");
        }
        __builtin_amdgcn_s_barrier();
        f32x4 acc[8] = {};
        __builtin_amdgcn_s_setprio(1);
#pragma unroll
        for (int kk = 0; kk < 4; ++kk) {
            bf16x8 af = *(const bf16x8*)&Ash[w * 16 + l16][(kk * 32 + quad * 8) ^ xr];
#pragma unroll
            for (int s = 0; s < 8; ++s) {
                bf16x8 bf = *(const bf16x8*)&Wsh[m & 1][s * 16 + l16][(kk * 32 + quad * 8) ^ xr];
                acc[s] = __builtin_amdgcn_mfma_f32_16x16x32_bf16(af, bf, acc[s], 0, 0, 0);
            }
        }
        __builtin_amdgcn_s_setprio(0);
        float bb[8];
#pragma unroll
        for (int s = 0; s < 8; ++s) bb[s] = ld1(bias, fbf, m0 + s * 16 + l16);
#pragma unroll
        for (int r = 0; r < 4; ++r) {
            int lr = w * 16 + quad * 4 + r;
            if (m == 2) {          // V: store transposed vt[(b*128+d)*SEQ + n]
                int n = n0 + lr;
                int bg = n >> 10, nl = n & 1023;
#pragma unroll
                for (int s = 0; s < 8; ++s)
                    vt[((size_t)(bg * 128) + s * 16 + l16) * SEQ + nl] =
                        f2bf(acc[s][r] + bb[s]);
            } else {
#pragma unroll
                for (int s = 0; s < 8; ++s)
                    qkv[(size_t)(n0 + lr) * QKVD + m0 + s * 16 + l16] =
                        f2bf(acc[s][r] + bb[s]);
            }
        }
        if (m < 2) __builtin_amdgcn_s_barrier();   // Wsh reuse guard
    }
}

// ===========================================================================
// K3 (batched): LDS flash attention, gload_lds K/V double-buffer.
// R10: Psh stride 72->76. Stride 72 put quads {0,2} and {1,3} in identical
// bank sets (quad*144 == {0,16,0,16} mod 32) -> 4-way write conflict
// (residual 425K SQ_LDS_BANK_CONFLICT). Stride 76: quad*152 == {0,24,16,8}.
// ===========================================================================
__global__ __launch_bounds__(256)
void attn2_kernel(const u16* __restrict__ qkv, const u16* __restrict__ vtp,
                  u16* __restrict__ ctx) {
    __shared__ __align__(16) u16 Qsh[64][72];
    __shared__ __align__(16) u16 Ksh[2][64][64];
    __shared__ __align__(16) u16 Vsh[2][64][64];
    __shared__ u16 Psh[64][76];
    int t    = threadIdx.x;
    int w    = t >> 6;
    int lane = t & 63;
    int l16  = lane & 15;
    int quad = lane >> 4;
    int xr   = (l16 & 7) << 3;
    int L = blockIdx.x;
    int ngh = gridDim.x >> 4;
    int qt, gh;
    if (ngh >= 8) {
        int g8 = L & 7; int rest = L >> 3;
        qt = rest & 15; gh = (rest >> 4) * 8 + g8;
    } else {
        qt = L & 15; gh = L >> 4;
    }
    int b = gh >> 1, h = gh & 1;

#pragma unroll
    for (int i = 0; i < 2; ++i) {
        int idx = t + i * 256;
        int r = idx >> 3, d8 = (idx & 7) * 8;
        size_t n = (size_t)b * SEQ + qt * 64 + r;
        float4 qv = *(const float4*)&qkv[n * QKVD + h * HDIM + d8];
        u16* qp = (u16*)&qv;
#pragma unroll
        for (int j = 0; j < 8; ++j) qp[j] = f2bf(bf2f(qp[j]) * 0.125f);
        *(float4*)&Qsh[r][d8] = qv;
    }

    const u16* kbase = qkv + (size_t)b * SEQ * QKVD + DIM + h * HDIM;
    const u16* vbase = vtp + (size_t)((b * 2 + h) * 64) * SEQ;

    auto stageKV = [&](int kt, int bf) {
#pragma unroll
        for (int i = 0; i < 2; ++i) {
            int r = w * 8 + i * 32 + (lane >> 3);
            int s = (lane & 7) ^ (r & 7);
            gload16(&kbase[(size_t)(kt * 64 + r) * QKVD + s * 8],
                    &Ksh[bf][w * 8 + i * 32][0]);
        }
#pragma unroll
        for (int i = 0; i < 2; ++i) {
            int r = w * 8 + i * 32 + (lane >> 3);
            int s = (lane & 7) ^ (r & 7);
            gload16(&vbase[(size_t)r * SEQ + kt * 64 + s * 8],
                    &Vsh[bf][w * 8 + i * 32][0]);
        }
    };

    stageKV(0, 0);
    VMCNT0();
    __syncthreads();
    bf16x8 qa0 = *(const bf16x8*)&Qsh[w * 16 + l16][quad * 8];
    bf16x8 qa1 = *(const bf16x8*)&Qsh[w * 16 + l16][32 + quad * 8];

    f32x4 o[4] = {};
    float mrow[4] = {-1e30f, -1e30f, -1e30f, -1e30f};
    float lrow[4] = {};

#pragma unroll 1
    for (int kt = 0; kt < SEQ / 64; ++kt) {
        int cur = kt & 1;
        if (kt + 1 < SEQ / 64) stageKV(kt + 1, cur ^ 1);

        float sc[4][4];
        __builtin_amdgcn_s_setprio(1);
#pragma unroll
        for (int c = 0; c < 4; ++c) {
            bf16x8 kb0 = *(const bf16x8*)&Ksh[cur][c * 16 + l16][(quad * 8) ^ xr];
            bf16x8 kb1 = *(const bf16x8*)&Ksh[cur][c * 16 + l16][(32 + quad * 8) ^ xr];
            f32x4 s = {};
            s = __builtin_amdgcn_mfma_f32_16x16x32_bf16(qa0, kb0, s, 0, 0, 0);
            s = __builtin_amdgcn_mfma_f32_16x16x32_bf16(qa1, kb1, s, 0, 0, 0);
#pragma unroll
            for (int r = 0; r < 4; ++r) sc[c][r] = s[r];
        }
        __builtin_amdgcn_s_setprio(0);
        float alpha[4];
#pragma unroll
        for (int r = 0; r < 4; ++r) {
            float mx = fmaxf(fmaxf(sc[0][r], sc[1][r]), fmaxf(sc[2][r], sc[3][r]));
            mx = row16_max(mx);
            float mnew = fmaxf(mrow[r], mx);
            alpha[r] = __expf(mrow[r] - mnew);
            mrow[r] = mnew;
            float sum = 0.f;
#pragma unroll
            for (int c = 0; c < 4; ++c) {
                float p = __expf(sc[c][r] - mnew);
                sc[c][r] = p;
                sum += p;
            }
            sum = row16_sum(sum);
            lrow[r] = lrow[r] * alpha[r] + sum;
        }
#pragma unroll
        for (int c = 0; c < 4; ++c)
#pragma unroll
            for (int r = 0; r < 4; ++r)
                Psh[w * 16 + quad * 4 + r][c * 16 + l16] = f2bf(sc[c][r]);
#pragma unroll
        for (int dt = 0; dt < 4; ++dt)
#pragma unroll
            for (int r = 0; r < 4; ++r) o[dt][r] *= alpha[r];
        bf16x8 pa0 = *(const bf16x8*)&Psh[w * 16 + l16][quad * 8];
        bf16x8 pa1 = *(const bf16x8*)&Psh[w * 16 + l16][32 + quad * 8];
        __builtin_amdgcn_s_setprio(1);
#pragma unroll
        for (int dt = 0; dt < 4; ++dt) {
            bf16x8 vb0 = *(const bf16x8*)&Vsh[cur][dt * 16 + l16][(quad * 8) ^ xr];
            bf16x8 vb1 = *(const bf16x8*)&Vsh[cur][dt * 16 + l16][(32 + quad * 8) ^ xr];
            o[dt] = __builtin_amdgcn_mfma_f32_16x16x32_bf16(pa0, vb0, o[dt], 0, 0, 0);
            o[dt] = __builtin_amdgcn_mfma_f32_16x16x32_bf16(pa1, vb1, o[dt], 0, 0, 0);
        }
        __builtin_amdgcn_s_setprio(0);
        if (kt + 1 < SEQ / 64) {
            VMCNT0();
            __syncthreads();
        }
    }
#pragma unroll
    for (int r = 0; r < 4; ++r) {
        float inv = 1.f / lrow[r];
        size_t n = (size_t)b * SEQ + qt * 64 + w * 16 + quad * 4 + r;
#pragma unroll
        for (int dt = 0; dt < 4; ++dt)
            ctx[n * DIM + h * HDIM + dt * 16 + l16] = f2bf(o[dt][r] * inv);
    }
}

// ===========================================================================
// K4 (batched): FUSED out-proj+LN1 + FFN + LN2.
// R10: h0 residual tile staged via gload16 into spare F1sh[1] region at
// kernel start (was 32 scalar stride-16 global loads/thread on the GEMM0
// epilogue critical path); read back via the proven XOR-layout pattern.
// vmcnt(8) after the 24-load issue leaves only W1c0 (newest 8) in flight.
// ===========================================================================
__global__ __launch_bounds__(256)
void outffn_kernel(const u16* __restrict__ ctx, const u16* __restrict__ Wout,
                   const void* __restrict__ out_b,
                   const void* __restrict__ l1g, const void* __restrict__ l1b,
                   const u16* __restrict__ h0,
                   const u16* __restrict__ W1, const u16* __restrict__ W2,
                   const void* __restrict__ b1, const void* __restrict__ b2,
                   const void* __restrict__ l2g, const void* __restrict__ l2b,
                   void* __restrict__ outp, const int* __restrict__ flag) {
    int fbf = *flag;
    int rs  = fbf ? 128 : 256;
    __shared__ __align__(16) u16 Ash[64][128];         // h1 tile (XOR layout)
    __shared__ __align__(16) u16 Wsh[2][128][128];     // weight double buffer
    __shared__ __align__(16) u16 F1sh[4][64][128];     // f1; phase-0 overlay below
    u16 (*CtxSh)[128]  = (u16(*)[128])&F1sh[0][0][0];  // 64 rows  (16KB)
    u16 (*H0Sh)[128]   = (u16(*)[128])&F1sh[1][0][0];  // 64 rows  (16KB)
    u16 (*WoutSh)[128] = (u16(*)[128])&F1sh[2][0][0];  // 128 rows (32KB)
    int t = threadIdx.x;
    int w = t >> 6, lane = t & 63, l16 = lane & 15, quad = lane >> 4;
    int n0 = blockIdx.x * 64;
    int xr = (l16 & 7) << 3;

    // issue: ctx tile (4/thr), Wout (8/thr), h0 tile (4/thr), W1 chunk0 (8/thr)
#pragma unroll
    for (int i = 0; i < 4; ++i) {
        int r = w * 4 + i * 16 + (lane >> 4);
        int s = (lane & 15) ^ (r & 7);
        gload16(&ctx[(size_t)(n0 + r) * DIM + s * 8], &CtxSh[w * 4 + i * 16][0]);
    }
#pragma unroll
    for (int i = 0; i < 8; ++i) {
        int r = w * 4 + i * 16 + (lane >> 4);
        int s = (lane & 15) ^ (r & 7);
        gload16(&Wout[(size_t)r * 128 + s * 8], &WoutSh[w * 4 + i * 16][0]);
    }
#pragma unroll
    for (int i = 0; i < 4; ++i) {
        int r = w * 4 + i * 16 + (lane >> 4);
        int s = (lane & 15) ^ (r & 7);
        gload16(&h0[(size_t)(n0 + r) * rs + s * 8], &H0Sh[w * 4 + i * 16][0]);
    }
#pragma unroll
    for (int i = 0; i < 8; ++i) {
        int r = w * 4 + i * 16 + (lane >> 4);
        int s = (lane & 15) ^ (r & 7);
        gload16(&W1[(size_t)r * 128 + s * 8], &Wsh[0][w * 4 + i * 16][0]);
    }
    asm volatile("s_waitcnt vmcnt(8)" ::: "memory");   // ctx+Wout+h0 landed; W1c0 in flight
    __builtin_amdgcn_s_barrier();

    // ---- GEMM0: h1 = ctx @ out_w^T (K=128) + bias + h0-resid + LN1 -> Ash ----
    {
        f32x4 acc[8] = {};
        __builtin_amdgcn_s_setprio(1);
#pragma unroll
        for (int kk = 0; kk < 4; ++kk) {
            bf16x8 af = *(const bf16x8*)&CtxSh[w * 16 + l16][(kk * 32 + quad * 8) ^ xr];
#pragma unroll
            for (int s = 0; s < 8; ++s) {
                bf16x8 bf = *(const bf16x8*)&WoutSh[s * 16 + l16][(kk * 32 + quad * 8) ^ xr];
                acc[s] = __builtin_amdgcn_mfma_f32_16x16x32_bf16(af, bf, acc[s], 0, 0, 0);
            }
        }
        __builtin_amdgcn_s_setprio(0);
        float bb[8], gg[8], be[8];
#pragma unroll
        for (int s = 0; s < 8; ++s) {
            bb[s] = ld1(out_b, fbf, s * 16 + l16);
            gg[s] = ld1(l1g, fbf, s * 16 + l16);
            be[s] = ld1(l1b, fbf, s * 16 + l16);
        }
#pragma unroll
        for (int r = 0; r < 4; ++r) {
            int lr = w * 16 + quad * 4 + r;
            float v[8];
#pragma unroll
            for (int s = 0; s < 8; ++s) {
                int e = s * 16 + l16;
                int g = e >> 3;
                float resid = bf2f(H0Sh[lr][((g ^ (lr & 7)) << 3) + (e & 7)]);
                v[s] = acc[s][r] + bb[s] + resid;
            }
            float sm = 0.f, sq = 0.f;
#pragma unroll
            for (int s = 0; s < 8; ++s) { sm += v[s]; sq += v[s] * v[s]; }
            sm = row16_sum(sm);
            sq = row16_sum(sq);
            float mu  = sm * (1.f / DIM);
            float var = fmaxf(sq * (1.f / DIM) - mu * mu, 0.f);
            float rsq = rsqrtf(var + 1e-5f);
#pragma unroll
            for (int s = 0; s < 8; ++s) {
                int e = s * 16 + l16;
                int g = e >> 3;
                Ash[lr][((g ^ (lr & 7)) << 3) + (e & 7)] =
                    f2bf((v[s] - mu) * rsq * gg[s] + be[s]);
            }
        }
        asm volatile("s_waitcnt lgkmcnt(0)" ::: "memory");
        __builtin_amdgcn_s_barrier();   // Ash ready; CtxSh/H0Sh/WoutSh consumed
    }

    // ---- GEMM1: 4 column tiles of ff1 -> F1sh (relu+bias, XOR layout) ----
#pragma unroll
    for (int m = 0; m < 4; ++m) {
#pragma unroll
        for (int i = 0; i < 8; ++i) {
            int r = w * 4 + i * 16 + (lane >> 4);
            int s = (lane & 15) ^ (r & 7);
            if (m < 3)
                gload16(&W1[(size_t)((m + 1) * 128 + r) * 128 + s * 8],
                        &Wsh[(m + 1) & 1][w * 4 + i * 16][0]);
            else
                gload16(&W2[(size_t)r * 512 + s * 8],
                        &Wsh[0][w * 4 + i * 16][0]);
        }
        asm volatile("s_waitcnt vmcnt(8)" ::: "memory");
        __builtin_amdgcn_s_barrier();
        f32x4 acc[8] = {};
        __builtin_amdgcn_s_setprio(1);
#pragma unroll
        for (int kk = 0; kk < 4; ++kk) {
            bf16x8 af = *(const bf16x8*)&Ash[w * 16 + l16][(kk * 32 + quad * 8) ^ xr];
#pragma unroll
            for (int s = 0; s < 8; ++s) {
                bf16x8 bf = *(const bf16x8*)&Wsh[m & 1][s * 16 + l16][(kk * 32 + quad * 8) ^ xr];
                acc[s] = __builtin_amdgcn_mfma_f32_16x16x32_bf16(af, bf, acc[s], 0, 0, 0);
            }
        }
        __builtin_amdgcn_s_setprio(0);
        float bb[8];
#pragma unroll
        for (int s = 0; s < 8; ++s) bb[s] = ld1(b1, fbf, m * 128 + s * 16 + l16);
#pragma unroll
        for (int r = 0; r < 4; ++r) {
            int lr = w * 16 + quad * 4 + r;
#pragma unroll
            for (int s = 0; s < 8; ++s) {
                int g = s * 2 + (l16 >> 3);
                F1sh[m][lr][((g ^ (lr & 7)) << 3) + (l16 & 7)] =
                    f2bf(fmaxf(acc[s][r] + bb[s], 0.f));
            }
        }
        asm volatile("s_waitcnt lgkmcnt(0)" ::: "memory");
        __builtin_amdgcn_s_barrier();
    }

    // ---- GEMM2: out = f1 @ ff2^T, K=512 in 4 LDS chunks ----
    f32x4 acc2[8] = {};
#pragma unroll
    for (int c = 0; c < 4; ++c) {
        if (c < 3) {
#pragma unroll
            for (int i = 0; i < 8; ++i) {
                int r = w * 4 + i * 16 + (lane >> 4);
                int s = (lane & 15) ^ (r & 7);
                gload16(&W2[(size_t)r * 512 + (c + 1) * 128 + s * 8],
                        &Wsh[(c + 1) & 1][w * 4 + i * 16][0]);
            }
            asm volatile("s_waitcnt vmcnt(8)" ::: "memory");
        } else {
            asm volatile("s_waitcnt vmcnt(0)" ::: "memory");
        }
        __builtin_amdgcn_s_barrier();
        __builtin_amdgcn_s_setprio(1);
#pragma unroll
        for (int kk = 0; kk < 4; ++kk) {
            bf16x8 af = *(const bf16x8*)&F1sh[c][w * 16 + l16][(kk * 32 + quad * 8) ^ xr];
#pragma unroll
            for (int s = 0; s < 8; ++s) {
                bf16x8 bf = *(const bf16x8*)&Wsh[c & 1][s * 16 + l16][(kk * 32 + quad * 8) ^ xr];
                acc2[s] = __builtin_amdgcn_mfma_f32_16x16x32_bf16(af, bf, acc2[s], 0, 0, 0);
            }
        }
        __builtin_amdgcn_s_setprio(0);
        if (c < 3) __builtin_amdgcn_s_barrier();
    }

    // ---- LN2 epilogue: +b2 +resid(h1 from Ash) -> final out ----
    float bb[8], gg[8], be[8];
#pragma unroll
    for (int s = 0; s < 8; ++s) {
        bb[s] = ld1(b2, fbf, s * 16 + l16);
        gg[s] = ld1(l2g, fbf, s * 16 + l16);
        be[s] = ld1(l2b, fbf, s * 16 + l16);
    }
#pragma unroll
    for (int r = 0; r < 4; ++r) {
        int lr = w * 16 + quad * 4 + r;
        size_t rg = (size_t)(n0 + lr);
        float v[8];
#pragma unroll
        for (int s = 0; s < 8; ++s) {
            int g = s * 2 + (l16 >> 3);
            float resid = bf2f(Ash[lr][((g ^ (lr & 7)) << 3) + (l16 & 7)]);
            v[s] = acc2[s][r] + bb[s] + resid;
        }
        float sm = 0.f, sq = 0.f;
#pragma unroll
        for (int s = 0; s < 8; ++s) { sm += v[s]; sq += v[s] * v[s]; }
        sm = row16_sum(sm);
        sq = row16_sum(sq);
        float mu  = sm * (1.f / DIM);
        float var = fmaxf(sq * (1.f / DIM) - mu * mu, 0.f);
        float rsq = rsqrtf(var + 1e-5f);
        if (fbf) {
            u16* o = (u16*)outp;
#pragma unroll
            for (int s = 0; s < 8; ++s)
                o[rg * 128 + s * 16 + l16] =
                    f2bf((v[s] - mu) * rsq * gg[s] + be[s]);
        } else {
            float* o = (float*)outp;
#pragma unroll
            for (int s = 0; s < 8; ++s)
                o[rg * 128 + s * 16 + l16] =
                    (v[s] - mu) * rsq * gg[s] + be[s];
        }
    }
}

// ============================================================================
//                 LEGACY KERNELS (per-graph fallback path)
// ============================================================================
template<int EPI, int NK>
__global__ __launch_bounds__(256)
void mgemm_kernel(const u16* __restrict__ A, const void* __restrict__ W,
                  int wbf16, const void* __restrict__ bias,
                  const u16* __restrict__ resid,
                  const void* __restrict__ lng, const void* __restrict__ lnb,
                  void* __restrict__ outp, u16* __restrict__ vt,
                  int Mtot, int AstrIn,
                  int arow0, int orow0, const int* __restrict__ flag) {
    const int K = NK * 128;
    int fbf  = *flag;
    int wfmt = wbf16 ? 1 : fbf;
    int rs   = fbf ? 128 : 256;
    int Astr = (AstrIn < 0) ? rs : AstrIn;
    __shared__ u16 Ash[64][136];
    __shared__ u16 Wsh[128][136];
    int t = threadIdx.x;
    int w = t >> 6, lane = t & 63, l16 = lane & 15, quad = lane >> 4;
    int n0 = blockIdx.x * 64;
    int m0 = blockIdx.y * 128;
    f32x4 acc[8] = {};
    float4 aR[4], wR[8];
#pragma unroll
    for (int i = 0; i < 4; ++i) {
        int idx = t + i * 256;
        int row = idx >> 4, k8 = (idx & 15) * 8;
        aR[i] = *(const float4*)&A[(size_t)(arow0 + n0 + row) * Astr + k8];
    }
#pragma unroll
    for (int i = 0; i < 8; ++i) {
        int idx = t + i * 256;
        int row = idx >> 4, k8 = (idx & 15) * 8;
        wR[i] = ldw8(W, wfmt, (size_t)(m0 + row) * K + k8);
    }
#pragma unroll 1
    for (int c = 0; c < NK; ++c) {
#pragma unroll
        for (int i = 0; i < 4; ++i) {
            int idx = t + i * 256;
            *(float4*)&Ash[idx >> 4][(idx & 15) * 8] = aR[i];
        }
#pragma unroll
        for (int i = 0; i < 8; ++i) {
            int idx = t + i * 256;
            *(float4*)&Wsh[idx >> 4][(idx & 15) * 8] = wR[i];
        }
        __syncthreads();
        if (c + 1 < NK) {
            int kc = (c + 1) * 128;
#pragma unroll
            for (int i = 0; i < 4; ++i) {
                int idx = t + i * 256;
                int row = idx >> 4, k8 = (idx & 15) * 8;
                aR[i] = *(const float4*)&A[(size_t)(arow0 + n0 + row) * Astr + kc + k8];
            }
#pragma unroll
            for (int i = 0; i < 8; ++i) {
                int idx = t + i * 256;
                int row = idx >> 4, k8 = (idx & 15) * 8;
                wR[i] = ldw8(W, wfmt, (size_t)(m0 + row) * K + kc + k8);
            }
        }
        __builtin_amdgcn_s_setprio(1);
#pragma unroll
        for (int kk = 0; kk < 4; ++kk) {
            bf16x8 af = *(const bf16x8*)&Ash[w * 16 + l16][kk * 32 + quad * 8];
#pragma unroll
            for (int s = 0; s < 8; ++s) {
                bf16x8 bf = *(const bf16x8*)&Wsh[s * 16 + l16][kk * 32 + quad * 8];
                acc[s] = __builtin_amdgcn_mfma_f32_16x16x32_bf16(af, bf, acc[s], 0, 0, 0);
            }
        }
        __builtin_amdgcn_s_setprio(0);
        if (c + 1 < NK) __syncthreads();
    }
    float bb[8];
#pragma unroll
    for (int s = 0; s < 8; ++s) bb[s] = ld1(bias, fbf, m0 + s * 16 + l16);
    float gg[8], be[8];
    if (EPI >= 2) {
#pragma unroll
        for (int s = 0; s < 8; ++s) {
            gg[s] = ld1(lng, fbf, s * 16 + l16);
            be[s] = ld1(lnb, fbf, s * 16 + l16);
        }
    }
#pragma unroll
    for (int r = 0; r < 4; ++r) {
        int lr = w * 16 + quad * 4 + r;
        float v[8];
#pragma unroll
        for (int s = 0; s < 8; ++s) {
            v[s] = acc[s][r] + bb[s];
            if (EPI == 1) v[s] = fmaxf(v[s], 0.f);
        }
        if (EPI <= 1) {
            u16* o = (u16*)outp;
#pragma unroll
            for (int s = 0; s < 8; ++s)
                o[(size_t)(n0 + lr) * Mtot + m0 + s * 16 + l16] = f2bf(v[s]);
        } else {
            size_t rg = (size_t)(orow0 + n0 + lr);
#pragma unroll
            for (int s = 0; s < 8; ++s)
                v[s] += bf2f(resid[rg * rs + s * 16 + l16]);
            float sm = 0.f, sq = 0.f;
#pragma unroll
            for (int s = 0; s < 8; ++s) { sm += v[s]; sq += v[s] * v[s]; }
            sm = row16_sum(sm);
            sq = row16_sum(sq);
            float mu  = sm * (1.f / DIM);
            float var = fmaxf(sq * (1.f / DIM) - mu * mu, 0.f);
            float rsq = rsqrtf(var + 1e-5f);
            if (EPI == 2) {
                u16* o = (u16*)outp;
#pragma unroll
                for (int s = 0; s < 8; ++s)
                    o[rg * rs + s * 16 + l16] =
                        f2bf((v[s] - mu) * rsq * gg[s] + be[s]);
            } else {
                if (fbf) {
                    u16* o = (u16*)outp;
#pragma unroll
                    for (int s = 0; s < 8; ++s)
                        o[rg * 128 + s * 16 + l16] =
                            f2bf((v[s] - mu) * rsq * gg[s] + be[s]);
                } else {
                    float* o = (float*)outp;
#pragma unroll
                    for (int s = 0; s < 8; ++s)
                        o[rg * 128 + s * 16 + l16] =
                            (v[s] - mu) * rsq * gg[s] + be[s];
                }
            }
        }
    }
}

__global__ __launch_bounds__(256)
void attn_lds_kernel(const u16* __restrict__ qkv, u16* __restrict__ ctx) {
    __shared__ u16 Qsh[64][72];
    __shared__ u16 Ksh[64][72];
    __shared__ u16 VshT[64][72];
    __shared__ u16 Psh[64][72];
    int t    = threadIdx.x;
    int w    = t >> 6;
    int lane = t & 63;
    int l16  = lane & 15;
    int quad = lane >> 4;
    int L = blockIdx.x;
    int qt = L & 15, gh = L >> 4;
    int b = gh >> 1, h = gh & 1;

#pragma unroll
    for (int i = 0; i < 2; ++i) {
        int idx = t + i * 256;
        int r = idx >> 3, d8 = (idx & 7) * 8;
        size_t n = (size_t)b * SEQ + qt * 64 + r;
        float4 qv = *(const float4*)&qkv[n * QKVD + h * HDIM + d8];
        u16* qp = (u16*)&qv;
#pragma unroll
        for (int j = 0; j < 8; ++j) qp[j] = f2bf(bf2f(qp[j]) * 0.125f);
        *(float4*)&Qsh[r][d8] = qv;
    }
    int kr = t >> 3, kd8 = (t & 7) * 8;
    int vr = t & 63, vdb = (t >> 6) * 16;
    float4 kR[2], vR[2];
    {
        size_t nk0 = (size_t)b * SEQ + kr;
        kR[0] = *(const float4*)&qkv[nk0 * QKVD + DIM + h * HDIM + kd8];
        kR[1] = *(const float4*)&qkv[(nk0 + 32) * QKVD + DIM + h * HDIM + kd8];
        size_t nv0 = (size_t)b * SEQ + vr;
        vR[0] = *(const float4*)&qkv[nv0 * QKVD + 2 * DIM + h * HDIM + vdb];
        vR[1] = *(const float4*)&qkv[nv0 * QKVD + 2 * DIM + h * HDIM + vdb + 8];
    }
    __syncthreads();
    bf16x8 qa0 = *(const bf16x8*)&Qsh[w * 16 + l16][quad * 8];
    bf16x8 qa1 = *(const bf16x8*)&Qsh[w * 16 + l16][32 + quad * 8];

    f32x4 o[4] = {};
    float mrow[4] = {-1e30f, -1e30f, -1e30f, -1e30f};
    float lrow[4] = {};

#pragma unroll 1
    for (int kt = 0; kt < SEQ / 64; ++kt) {
        *(float4*)&Ksh[kr][kd8]      = kR[0];
        *(float4*)&Ksh[kr + 32][kd8] = kR[1];
        {
            const u16* pa = (const u16*)&vR[0];
            const u16* pb = (const u16*)&vR[1];
#pragma unroll
            for (int j = 0; j < 8; ++j) VshT[vdb + j][vr] = pa[j];
#pragma unroll
            for (int j = 0; j < 8; ++j) VshT[vdb + 8 + j][vr] = pb[j];
        }
        __syncthreads();
        if (kt + 1 < SEQ / 64) {
            size_t nk0 = (size_t)b * SEQ + (kt + 1) * 64 + kr;
            kR[0] = *(const float4*)&qkv[nk0 * QKVD + DIM + h * HDIM + kd8];
            kR[1] = *(const float4*)&qkv[(nk0 + 32) * QKVD + DIM + h * HDIM + kd8];
            size_t nv0 = (size_t)b * SEQ + (kt + 1) * 64 + vr;
            vR[0] = *(const float4*)&qkv[nv0 * QKVD + 2 * DIM + h * HDIM + vdb];
            vR[1] = *(const float4*)&qkv[nv0 * QKVD + 2 * DIM + h * HDIM + vdb + 8];
        }
        float sc[4][4];
        __builtin_amdgcn_s_setprio(1);
#pragma unroll
        for (int c = 0; c < 4; ++c) {
            bf16x8 kb0 = *(const bf16x8*)&Ksh[c * 16 + l16][quad * 8];
            bf16x8 kb1 = *(const bf16x8*)&Ksh[c * 16 + l16][32 + quad * 8];
            f32x4 s = {};
            s = __builtin_amdgcn_mfma_f32_16x16x32_bf16(qa0, kb0, s, 0, 0, 0);
            s = __builtin_amdgcn_mfma_f32_16x16x32_bf16(qa1, kb1, s, 0, 0, 0);
#pragma unroll
            for (int r = 0; r < 4; ++r) sc[c][r] = s[r];
        }
        __builtin_amdgcn_s_setprio(0);
        float alpha[4];
#pragma unroll
        for (int r = 0; r < 4; ++r) {
            float mx = fmaxf(fmaxf(sc[0][r], sc[1][r]), fmaxf(sc[2][r], sc[3][r]));
            mx = row16_max(mx);
            float mnew = fmaxf(mrow[r], mx);
            alpha[r] = __expf(mrow[r] - mnew);
            mrow[r] = mnew;
            float sum = 0.f;
#pragma unroll
            for (int c = 0; c < 4; ++c) {
                float p = __expf(sc[c][r] - mnew);
                sc[c][r] = p;
                sum += p;
            }
            sum = row16_sum(sum);
            lrow[r] = lrow[r] * alpha[r] + sum;
        }
#pragma unroll
        for (int c = 0; c < 4; ++c)
#pragma unroll
            for (int r = 0; r < 4; ++r)
                Psh[w * 16 + quad * 4 + r][c * 16 + l16] = f2bf(sc[c][r]);
#pragma unroll
        for (int dt = 0; dt < 4; ++dt)
#pragma unroll
            for (int r = 0; r < 4; ++r) o[dt][r] *= alpha[r];
        bf16x8 pa0 = *(const bf16x8*)&Psh[w * 16 + l16][quad * 8];
        bf16x8 pa1 = *(const bf16x8*)&Psh[w * 16 + l16][32 + quad * 8];
        __builtin_amdgcn_s_setprio(1);
#pragma unroll
        for (int dt = 0; dt < 4; ++dt) {
            bf16x8 vb0 = *(const bf16x8*)&VshT[dt * 16 + l16][quad * 8];
            bf16x8 vb1 = *(const bf16x8*)&VshT[dt * 16 + l16][32 + quad * 8];
            o[dt] = __builtin_amdgcn_mfma_f32_16x16x32_bf16(pa0, vb0, o[dt], 0, 0, 0);
            o[dt] = __builtin_amdgcn_mfma_f32_16x16x32_bf16(pa1, vb1, o[dt], 0, 0, 0);
        }
        __builtin_amdgcn_s_setprio(0);
        __syncthreads();
    }
#pragma unroll
    for (int r = 0; r < 4; ++r) {
        float inv = 1.f / lrow[r];
        size_t n = (size_t)b * SEQ + qt * 64 + w * 16 + quad * 4 + r;
#pragma unroll
        for (int dt = 0; dt < 4; ++dt)
            ctx[n * DIM + h * HDIM + dt * 16 + l16] = f2bf(o[dt][r] * inv);
    }
}

// ---------------------------------------------------------------------------
extern "C" void kernel_launch(void* const* d_in, const int* in_sizes, int n_in,
                              void* d_out, int out_size, void* d_ws, size_t ws_size,
                              hipStream_t stream) {
    const void* x     = d_in[0];
    const void* pos   = d_in[1];
    const void* pe_w  = d_in[2];
    const void* pe_b  = d_in[3];
    const void* in_w  = d_in[4];
    const void* in_b  = d_in[5];
    const void* out_w = d_in[6];
    const void* out_b = d_in[7];
    const void* ln1_g = d_in[8];
    const void* ln1_b = d_in[9];
    const void* ln2_g = d_in[10];
    const void* ln2_b = d_in[11];
    const void* ff1_w = d_in[12];
    const void* ff1_b = d_in[13];
    const void* ff2_w = d_in[14];
    const void* ff2_b = d_in[15];

    char* wsb  = (char*)d_ws;
    int*  flag = (int*)(wsb + ((ws_size - 4) & ~(size_t)3));
    u16*  h01  = (u16*)d_out;   // h0 bf16 in dtype-dependent row slots
    const size_t MB = 1024 * 1024;

    if (ws_size >= 21 * MB) {
        // batched path: qkv[0,12M), ctx[12,16M), vt[16,20M), wbf[20M,+384K)
        u16* qkv = (u16*)wsb;
        u16* ctx = (u16*)(wsb + 12 * MB);
        u16* vt  = (u16*)(wsb + 16 * MB);
        u16* wbf = (u16*)(wsb + 20 * MB);
        u16* wb_in  = wbf;
        u16* wb_out = wbf + 49152;
        u16* wb_ff1 = wbf + 65536;
        u16* wb_ff2 = wbf + 131072;

        wconv_kernel<<<96, 256, 0, stream>>>(in_w, out_w, ff1_w, ff2_w,
                                             (const u16*)x, wbf, flag);
        qkvpe_kernel<<<NTOT / 64, 256, 0, stream>>>(
            x, pos, pe_w, pe_b, wb_in, in_b, h01, qkv, vt, flag);
        attn2_kernel<<<NGRAPH * NHEAD * 16, 256, 0, stream>>>(qkv, vt, ctx);
        outffn_kernel<<<NTOT / 64, 256, 0, stream>>>(
            ctx, wb_out, out_b, ln1_g, ln1_b, h01,
            wb_ff1, wb_ff2, ff1_b, ff2_b, ln2_g, ln2_b, d_out, flag);
    } else {
        // per-graph path (legacy): qkv_g[0,768K), ctx_g[768K,1M); f1_g reuse
        u16* qkv_g = (u16*)wsb;
        u16* ctx_g = (u16*)(wsb + 768 * 1024);
        u16* f1_g  = (u16*)wsb;
        detect_kernel<<<1, 1, 0, stream>>>((const u16*)x, flag);
        pe_kernel<<<NTOT / 2, 256, 0, stream>>>(x, pos, pe_w, pe_b, h01, flag);
        for (int g = 0; g < NGRAPH; ++g) {
            int row0 = g * SEQ;
            mgemm_kernel<0,1><<<dim3(SEQ / 64, 3), 256, 0, stream>>>(
                h01, in_w, 0, in_b, nullptr, nullptr, nullptr, qkv_g, nullptr,
                QKVD, -1, row0, 0, flag);
            attn_lds_kernel<<<NHEAD * 16, 256, 0, stream>>>(qkv_g, ctx_g);
            mgemm_kernel<2,1><<<dim3(SEQ / 64, 1), 256, 0, stream>>>(
                ctx_g, out_w, 0, out_b, h01, ln1_g, ln1_b, h01, nullptr,
                DIM, DIM, 0, row0, flag);
        }
        for (int g = 0; g < NGRAPH; ++g) {
            int row0 = g * SEQ;
            mgemm_kernel<1,1><<<dim3(SEQ / 64, 4), 256, 0, stream>>>(
                h01, ff1_w, 0, ff1_b, nullptr, nullptr, nullptr, f1_g, nullptr,
                4 * DIM, -1, row0, 0, flag);
            mgemm_kernel<3,4><<<dim3(SEQ / 64, 1), 256, 0, stream>>>(
                f1_g, ff2_w, 0, ff2_b, h01, ln2_g, ln2_b, d_out, nullptr,
                DIM, 4 * DIM, 0, row0, flag);
        }
    }
}